// Round 4
// baseline (215.330 us; speedup 1.0000x reference)
//
#include <hip/hip_runtime.h>

// Problem constants
#define DIMC 1024
#define SEQL 2048
#define NB   2
#define NH   16
#define HD   64
#define MTOT (NB*SEQL)          // 4096 rows
#define XSTR 2048               // q/k interleaved in x buffer: [q 1024 | k 1024] per row
static constexpr float SM_SCALE = 0.125f;             // HEAD_DIM^-0.5
static constexpr float LOG2E    = 1.4426950408889634f;
static constexpr float QSCALE   = SM_SCALE * LOG2E;   // folded into q at projection

typedef short s16x8 __attribute__((ext_vector_type(8)));
typedef short s16x4 __attribute__((ext_vector_type(4)));
typedef float f32x4 __attribute__((ext_vector_type(4)));
typedef int   i32x4 __attribute__((ext_vector_type(4)));

__device__ __forceinline__ unsigned short f2bf(float f) {
    unsigned int u = __float_as_uint(f);
    u += 0x7fffu + ((u >> 16) & 1u);   // round-to-nearest-even
    return (unsigned short)(u >> 16);
}
__device__ __forceinline__ s16x8 ld8(const unsigned short* p) {
    return *(const s16x8*)p;           // 16B global_load_dwordx4 (bf16 x8)
}
// async global->LDS, 16B per lane
__device__ __forceinline__ void gld_lds16(const unsigned short* g, unsigned short* l) {
    __builtin_amdgcn_global_load_lds(
        (const __attribute__((address_space(1))) void*)g,
        (__attribute__((address_space(3))) void*)l, 16, 0, 0);
}
// pack two f32 -> one u32 of 2x bf16 (RNE); no builtin on gfx950
__device__ __forceinline__ unsigned int cvtpk(float lo, float hi) {
    unsigned int r;
    asm("v_cvt_pk_bf16_f32 %0, %1, %2" : "=v"(r) : "v"(lo), "v"(hi));
    return r;
}

#define BAR()    asm volatile("s_barrier" ::: "memory")
#define WAITVM4() asm volatile("s_waitcnt vmcnt(4)" ::: "memory")
#define WAITVM0() asm volatile("s_waitcnt vmcnt(0)" ::: "memory")

// ---------------------------------------------------------------------------
// One-shot prep: x -> bf16 (blocks 0..4095), W's -> bf16 (blocks 4096..8191),
// qkv bias pack fp32 (blocks 8192+).
// ---------------------------------------------------------------------------
__global__ __launch_bounds__(256) void cast_all(
    const float* __restrict__ x,
    const float* __restrict__ Wq, const float* __restrict__ Wk,
    const float* __restrict__ Wv, const float* __restrict__ Wp,
    const float* __restrict__ bq, const float* __restrict__ bk,
    const float* __restrict__ bvv,
    unsigned short* __restrict__ xb, unsigned short* __restrict__ wall,
    float* __restrict__ ball)
{
    const int bid = blockIdx.x, tid = threadIdx.x;
    if (bid < 4096) {
        int i = bid * 256 + tid;                 // x: 1M float4
        float4 f = ((const float4*)x)[i];
        s16x4 o;
        o[0] = (short)f2bf(f.x); o[1] = (short)f2bf(f.y);
        o[2] = (short)f2bf(f.z); o[3] = (short)f2bf(f.w);
        ((s16x4*)xb)[i] = o;
    } else if (bid < 8192) {
        int j = (bid - 4096) * 256 + tid;        // W: 1M float4 over 4 mats
        int r = j >> 18;                         // 256K float4 per matrix
        const float* src = (r == 0) ? Wq : (r == 1) ? Wk : (r == 2) ? Wv : Wp;
        float4 f = ((const float4*)src)[j & 262143];
        s16x4 o;
        o[0] = (short)f2bf(f.x); o[1] = (short)f2bf(f.y);
        o[2] = (short)f2bf(f.z); o[3] = (short)f2bf(f.w);
        ((s16x4*)wall)[j] = o;
    } else {
        int t2 = (bid - 8192) * 256 + tid;
        if (t2 < 3072)
            ball[t2] = (t2 < 1024) ? bq[t2]
                     : (t2 < 2048) ? bk[t2 - 1024] : bvv[t2 - 2048];
    }
}

// ---------------------------------------------------------------------------
// 128x128-tile NT GEMM, K=1024, BK=32, 256 threads.
// R15: double-buffered LDS + unroll-2 + raw s_barrier + counted vmcnt(4)
// (the pattern verified in attn_fused): prefetch for step k+1 rides across
// the barrier while compute(k) runs; the wait only drains the buffer about
// to be consumed. s_setprio(1) around the MFMA cluster. Epilogue unchanged.
// XCD-pinned nt-chunks (nt_total % 8 == 0 for both call sites).
// mode 0 (QKV fused, N=3072): nt 0..7 -> q (scaled by QSCALE), 8..15 -> k,
//   16..23 -> v^T into vtb (b,h,d,l).  bias[proj*1024 + col].
// mode 1 (out-proj, N=1024): fp32 store to outf, bias[col].
// ---------------------------------------------------------------------------
__global__ __launch_bounds__(256) void gemm_tile(
    const unsigned short* __restrict__ A, int astride,
    const unsigned short* __restrict__ Wb,
    const float* __restrict__ bias,
    unsigned short* qk, unsigned short* vtb, float* outf, int mode)
{
    __shared__ __align__(16) unsigned short Asm[2][128 * 32];   // 2x8 KB
    __shared__ __align__(16) unsigned short Bsm[2][128 * 32];   // 2x8 KB

    const int t    = threadIdx.x;
    const int lane = t & 63;
    const int l15  = lane & 15;
    const int quad = lane >> 4;
    const int w    = t >> 6;
    const int mrow = (w & 1) * 64;
    const int ncol = (w >> 1) * 64;
    // XCD-pinned mapping: bid = i2*8 + xcd; nt chunked per XCD (bijective,
    // requires gridDim.x/32 % 8 == 0 -- holds for 24 and 8).
    const int nt_total = (int)gridDim.x >> 5;
    const int xcd = blockIdx.x & 7;
    const int i2  = blockIdx.x >> 3;
    const int nt  = xcd * (nt_total >> 3) + (i2 >> 5);
    const int mt  = i2 & 31;
    const int row0 = mt * 128;

    const unsigned short* ga = A  + (size_t)(row0 + (t >> 2)) * astride + (t & 3) * 8;
    const unsigned short* gb = Wb + (size_t)(nt * 128 + (t >> 2)) * DIMC + (t & 3) * 8;
    const size_t gaStep = (size_t)64 * astride;
    const size_t gbStep = (size_t)64 * DIMC;

    f32x4 acc[4][4] = {};

    // stage one BK=32 step (A+B halves) into buffer pair; 4 loads per thread
    auto stage = [&](unsigned short* Ab, unsigned short* Bb, int k0) {
        gld_lds16(ga + k0,          Ab + t * 8);
        gld_lds16(ga + gaStep + k0, Ab + 2048 + t * 8);
        gld_lds16(gb + k0,          Bb + t * 8);
        gld_lds16(gb + gbStep + k0, Bb + 2048 + t * 8);
    };

    // consume one staged step (compile-time buffer pointers)
    auto compute = [&](const unsigned short* Ac, const unsigned short* Bc) {
        s16x8 a[4], b[4];
#pragma unroll
        for (int mi = 0; mi < 4; ++mi)
            a[mi] = *(const s16x8*)(Ac + (mrow + mi * 16 + l15) * 32 + quad * 8);
#pragma unroll
        for (int ni = 0; ni < 4; ++ni)
            b[ni] = *(const s16x8*)(Bc + (ncol + ni * 16 + l15) * 32 + quad * 8);
        __builtin_amdgcn_s_setprio(1);
#pragma unroll
        for (int mi = 0; mi < 4; ++mi)
#pragma unroll
            for (int ni = 0; ni < 4; ++ni)
                acc[mi][ni] = __builtin_amdgcn_mfma_f32_16x16x32_bf16(
                    a[mi], b[ni], acc[mi][ni], 0, 0, 0);
        __builtin_amdgcn_s_setprio(0);
    };

    // prologue: stage step 0 into buffer 0
    stage(Asm[0], Bsm[0], 0);

    // Steady state: exactly 4 loads in flight across each barrier; vmcnt(4)
    // waits only for the buffer about to be consumed (issued one full compute
    // phase earlier), never draining the just-issued prefetch. WAR on a
    // buffer is protected by the trailing barrier of the body that read it.
#pragma unroll 1
    for (int k0 = 0; k0 < DIMC; k0 += 64) {
        // body A: prefetch step k0+32 -> buf1, compute buf0 (step k0)
        stage(Asm[1], Bsm[1], k0 + 32);
        WAITVM4();
        BAR();
        compute(Asm[0], Bsm[0]);
        BAR();
        // body B: prefetch step k0+64 -> buf0, compute buf1 (step k0+32)
        if (k0 + 64 < DIMC) {
            stage(Asm[0], Bsm[0], k0 + 64);
            WAITVM4();
        } else {
            WAITVM0();
        }
        BAR();
        compute(Asm[1], Bsm[1]);
        BAR();
    }

    const int proj = nt >> 3;                  // mode0: 0=q 1=k 2=v ; mode1: 0
#pragma unroll
    for (int ni = 0; ni < 4; ++ni) {
        const int cq = (nt & 7) * 128 + ncol + ni * 16 + l15;   // col within proj
        const float bz = bias[proj * 1024 + cq];
#pragma unroll
        for (int mi = 0; mi < 4; ++mi) {
            const int rbase = row0 + mrow + mi * 16 + quad * 4;
            if (mode == 0) {
                if (proj < 2) {
                    const float scale = (proj == 0) ? QSCALE : 1.0f;
#pragma unroll
                    for (int r = 0; r < 4; ++r)
                        qk[(size_t)(rbase + r) * XSTR + proj * DIMC + cq] =
                            f2bf((acc[mi][ni][r] + bz) * scale);
                } else {
                    const int h = cq >> 6, d = cq & 63;
                    const int bb = rbase >> 11, ll = rbase & (SEQL - 1);
                    s16x4 v4;
                    v4[0] = (short)f2bf(acc[mi][ni][0] + bz);
                    v4[1] = (short)f2bf(acc[mi][ni][1] + bz);
                    v4[2] = (short)f2bf(acc[mi][ni][2] + bz);
                    v4[3] = (short)f2bf(acc[mi][ni][3] + bz);
                    *(s16x4*)(vtb + ((size_t)((bb * NH + h) * HD + d)) * SEQL + ll) = v4;
                }
            } else {
#pragma unroll
                for (int r = 0; r < 4; ++r)
                    outf[(size_t)(rbase + r) * DIMC + cq] = acc[mi][ni][r] + bz;
            }
        }
    }
}

// ---------------------------------------------------------------------------
// Flash attention v9 (verified in R15 bench): 256-thr blocks, 4 waves,
// 128 q-rows share one K/V staging; unroll-2 double buffer + raw s_barrier +
// counted vmcnt(4); s_setprio(1) around the MFMA/softmax cluster; l via
// all-ones-B MFMA; P-pack via v_cvt_pk_bf16_f32. UNCHANGED from R15.
// ---------------------------------------------------------------------------
__global__ __launch_bounds__(256) void attn_fused(
    unsigned short* xqk,
    const unsigned short* __restrict__ vt)
{
    __shared__ __align__(16) unsigned short Ksm[2][64 * 64];   // 2x8 KB [key][d] swizzled
    __shared__ __align__(16) unsigned short Vsm[2][64 * 64];   // 2x8 KB [d][key] swizzled

    const int t    = threadIdx.x;
    const int lane = t & 63;
    const int l15  = lane & 15;
    const int quad = lane >> 4;
    const int w    = t >> 6;                 // wave 0..3

    // XCD-pinned mapping (bijective: bid = ii*8 + xcd), 512 blocks
    const int xcd = blockIdx.x & 7;
    const int ii  = blockIdx.x >> 3;         // 0..63
    const int bh  = (xcd << 2) | (ii >> 4);  // all 16 q-blocks of a bh on one XCD
    const int qb  = ii & 15;                 // 128-row q-block
    const int h  = bh & (NH - 1);
    const int bb = bh >> 4;
    const int q0A = qb * 128 + w * 16;       // wave's two q-tiles
    const int q0B = q0A + 64;

    // Q B-frags (lane&15 = q row), loaded before any O store (in-place safe)
    unsigned short* qbase = xqk + (size_t)(bb * SEQL) * XSTR + h * HD + quad * 8;
    unsigned short* qrA = qbase + (size_t)(q0A + l15) * XSTR;
    unsigned short* qrB = qbase + (size_t)(q0B + l15) * XSTR;
    const s16x8 bqA0 = ld8(qrA), bqA1 = ld8(qrA + 32);
    const s16x8 bqB0 = ld8(qrB), bqB1 = ld8(qrB + 32);

    // all-ones bf16 B-frag for the l-accumulation MFMA
    s16x8 bones;
#pragma unroll
    for (int e = 0; e < 8; ++e) bones[e] = (short)0x3F80;

    // staging: 256 threads cover a 64x64 tile in 2 row-groups of 32.
    // thread t: row-in-group tr = t>>3 (0..31), chunk pos tp = t&7; source
    // chunk XOR-swizzled so LDS pos p of row r holds logical chunk p^(r&7)
    // (r = tr + g*32; r&7 == tr&7 since 32 = 0 mod 8).
    const int tr = t >> 3, tp = t & 7;
    const int swz = (tp ^ (tr & 7)) * 8;
    const unsigned short* kg = xqk + (size_t)bb * SEQL * XSTR + DIMC + h * HD
                               + (size_t)tr * XSTR + swz;
    const unsigned short* vg = vt + (size_t)(bh * HD + tr) * SEQL + swz;

    f32x4 oA[4] = {}, oB[4] = {};
    f32x4 laccA = {}, laccB = {};            // row-sums of P (denominators)
    const int xk = l15 & 7;

    // stage one 64-key tile (K + V) into buffer buf; 4 loads per thread
    auto stage = [&](unsigned short* Kb, unsigned short* Vb, int j) {
#pragma unroll
        for (int g = 0; g < 2; ++g) {
            gld_lds16(kg + (size_t)(j + g * 32) * XSTR, Kb + g * 2048 + t * 8);
            gld_lds16(vg + (size_t)(g * 32) * SEQL + j,  Vb + g * 2048 + t * 8);
        }
    };

    // compute one 64-key tile from buffers (compile-time pointers)
    auto compute = [&](const unsigned short* Kc, const unsigned short* Vc) {
#pragma unroll
        for (int hf = 0; hf < 2; ++hf) {
            // K A-frags for two 16-key sub-blocks (shared by both q-tiles)
            const int k0 = (hf * 32 + l15) * 64;
            const int k1 = (hf * 32 + 16 + l15) * 64;
            s16x8 a00 = *(const s16x8*)(Kc + k0 + ((quad       ^ xk) * 8));
            s16x8 a01 = *(const s16x8*)(Kc + k0 + (((quad + 4) ^ xk) * 8));
            s16x8 a10 = *(const s16x8*)(Kc + k1 + ((quad       ^ xk) * 8));
            s16x8 a11 = *(const s16x8*)(Kc + k1 + (((quad + 4) ^ xk) * 8));

            // V B-frags with the key permutation (shared by both q-tiles)
            s16x8 bv[4];
#pragma unroll
            for (int c = 0; c < 4; ++c) {
                const unsigned short* va = Vc + (c * 16 + l15) * 64 + (quad & 1) * 4;
                const int kc0 = hf * 4 + (quad >> 1);
                s16x4 v0 = *(const s16x4*)(va + ((kc0       ^ xk) * 8));
                s16x4 v1 = *(const s16x4*)(va + (((kc0 + 2) ^ xk) * 8));
                bv[c] = __builtin_shufflevector(v0, v1, 0, 1, 2, 3, 4, 5, 6, 7);
            }

            __builtin_amdgcn_s_setprio(1);
            // q-tile A
            {
                f32x4 st0 = {}, st1 = {};
                st0 = __builtin_amdgcn_mfma_f32_16x16x32_bf16(a00, bqA0, st0, 0, 0, 0);
                st0 = __builtin_amdgcn_mfma_f32_16x16x32_bf16(a01, bqA1, st0, 0, 0, 0);
                st1 = __builtin_amdgcn_mfma_f32_16x16x32_bf16(a10, bqA0, st1, 0, 0, 0);
                st1 = __builtin_amdgcn_mfma_f32_16x16x32_bf16(a11, bqA1, st1, 0, 0, 0);
                i32x4 api;
                api[0] = (int)cvtpk(__builtin_amdgcn_exp2f(st0[0]),
                                    __builtin_amdgcn_exp2f(st0[1]));
                api[1] = (int)cvtpk(__builtin_amdgcn_exp2f(st0[2]),
                                    __builtin_amdgcn_exp2f(st0[3]));
                api[2] = (int)cvtpk(__builtin_amdgcn_exp2f(st1[0]),
                                    __builtin_amdgcn_exp2f(st1[1]));
                api[3] = (int)cvtpk(__builtin_amdgcn_exp2f(st1[2]),
                                    __builtin_amdgcn_exp2f(st1[3]));
                s16x8 ap = __builtin_bit_cast(s16x8, api);
                laccA = __builtin_amdgcn_mfma_f32_16x16x32_bf16(ap, bones, laccA, 0, 0, 0);
#pragma unroll
                for (int c = 0; c < 4; ++c)
                    oA[c] = __builtin_amdgcn_mfma_f32_16x16x32_bf16(ap, bv[c], oA[c], 0, 0, 0);
            }
            // q-tile B
            {
                f32x4 st0 = {}, st1 = {};
                st0 = __builtin_amdgcn_mfma_f32_16x16x32_bf16(a00, bqB0, st0, 0, 0, 0);
                st0 = __builtin_amdgcn_mfma_f32_16x16x32_bf16(a01, bqB1, st0, 0, 0, 0);
                st1 = __builtin_amdgcn_mfma_f32_16x16x32_bf16(a10, bqB0, st1, 0, 0, 0);
                st1 = __builtin_amdgcn_mfma_f32_16x16x32_bf16(a11, bqB1, st1, 0, 0, 0);
                i32x4 api;
                api[0] = (int)cvtpk(__builtin_amdgcn_exp2f(st0[0]),
                                    __builtin_amdgcn_exp2f(st0[1]));
                api[1] = (int)cvtpk(__builtin_amdgcn_exp2f(st0[2]),
                                    __builtin_amdgcn_exp2f(st0[3]));
                api[2] = (int)cvtpk(__builtin_amdgcn_exp2f(st1[0]),
                                    __builtin_amdgcn_exp2f(st1[1]));
                api[3] = (int)cvtpk(__builtin_amdgcn_exp2f(st1[2]),
                                    __builtin_amdgcn_exp2f(st1[3]));
                s16x8 ap = __builtin_bit_cast(s16x8, api);
                laccB = __builtin_amdgcn_mfma_f32_16x16x32_bf16(ap, bones, laccB, 0, 0, 0);
#pragma unroll
                for (int c = 0; c < 4; ++c)
                    oB[c] = __builtin_amdgcn_mfma_f32_16x16x32_bf16(ap, bv[c], oB[c], 0, 0, 0);
            }
            __builtin_amdgcn_s_setprio(0);
        }
    };

    // prologue: stage tile 0 into buffer 0
    stage(Ksm[0], Vsm[0], 0);

    // main loop: unroll-2 so buffer pointers are compile-time constants.
#pragma unroll 1
    for (int jt = 0; jt < SEQL / 64; jt += 2) {
        const int j0 = jt * 64;
        // body A: prefetch tile jt+1 -> buf1, compute buf0 (tile jt)
        stage(Ksm[1], Vsm[1], j0 + 64);
        WAITVM4();
        BAR();
        compute(Ksm[0], Vsm[0]);
        BAR();
        // body B: prefetch tile jt+2 -> buf0, compute buf1 (tile jt+1)
        if (jt + 2 < SEQL / 64) {
            stage(Ksm[0], Vsm[0], j0 + 128);
            WAITVM4();
        } else {
            WAITVM0();
        }
        BAR();
        compute(Ksm[1], Vsm[1]);
        BAR();
    }

    // laccX[r] = l for q-row quad*4+r (replicated across l15) -> no shuffles
    float liA[4], liB[4];
#pragma unroll
    for (int r = 0; r < 4; ++r) {
        liA[r] = 1.0f / laccA[r];
        liB[r] = 1.0f / laccB[r];
    }

#pragma unroll
    for (int c = 0; c < 4; ++c) {
        const int d = c * 16 + l15;
#pragma unroll
        for (int r = 0; r < 4; ++r) {
            const int qr = quad * 4 + r;
            xqk[(size_t)(bb * SEQL + q0A + qr) * XSTR + h * HD + d] = f2bf(oA[c][r] * liA[r]);
            xqk[(size_t)(bb * SEQL + q0B + qr) * XSTR + h * HD + d] = f2bf(oB[c][r] * liB[r]);
        }
    }
}

// ---------------------------------------------------------------------------
// ws layout (u16 elems): xb [0,4M) | Wq|Wk|Wv|Wp [4M,8M) | bias fp32 @ 8M.
// q (pre-scaled by 0.125*log2e), k -> x's buffer; V^T -> d_out (dead before
// out-proj); attn-out in-place over q slots; final fp32 out -> d_out.
// ---------------------------------------------------------------------------
extern "C" void kernel_launch(void* const* d_in, const int* in_sizes, int n_in,
                              void* d_out, int out_size, void* d_ws, size_t ws_size,
                              hipStream_t stream) {
    const float* x  = (const float*)d_in[0];
    const float* Wq = (const float*)d_in[1];
    const float* bq = (const float*)d_in[2];
    const float* Wk = (const float*)d_in[3];
    const float* bk = (const float*)d_in[4];
    const float* Wv = (const float*)d_in[5];
    const float* bv = (const float*)d_in[6];
    const float* Wp = (const float*)d_in[7];
    const float* bp = (const float*)d_in[8];
    float* out = (float*)d_out;
    unsigned short* vtb = (unsigned short*)d_out;
    unsigned short* xqk = (unsigned short*)d_in[0];

    unsigned short* ws   = (unsigned short*)d_ws;
    const size_t XELT = (size_t)MTOT * DIMC;     // 4M
    const size_t WELT = (size_t)DIMC * DIMC;     // 1M
    unsigned short* xb   = ws;
    unsigned short* wall = ws + XELT;
    float*          ball = (float*)(ws + 2 * XELT);

    cast_all<<<8204, 256, 0, stream>>>(x, Wq, Wk, Wv, Wp, bq, bk, bv, xb, wall, ball);

    // fused QKV GEMM: M=4096, N=3072 -> 32 x 24 tiles = 768 blocks
    gemm_tile<<<768, 256, 0, stream>>>(xb, DIMC, wall, ball, xqk, vtb, nullptr, 0);

    // attention: 512 blocks (32 bh x 16 q-blocks of 128 rows), 4 waves each
    attn_fused<<<NB * NH * (SEQL / 128), 256, 0, stream>>>(xqk, vtb);

    // out-proj: M=4096, N=1024 -> 256 blocks, fp32 out
    gemm_tile<<<256, 256, 0, stream>>>(xqk, XSTR, wall + 3 * WELT, bp,
                                       nullptr, nullptr, out, 1);
}

// Round 5
// 212.435 us; speedup vs baseline: 1.0136x; 1.0136x over previous
//
#include <hip/hip_runtime.h>

// Problem constants
#define DIMC 1024
#define SEQL 2048
#define NB   2
#define NH   16
#define HD   64
#define MTOT (NB*SEQL)          // 4096 rows
#define XSTR 2048               // q/k interleaved in x buffer: [q 1024 | k 1024] per row
static constexpr float SM_SCALE = 0.125f;             // HEAD_DIM^-0.5
static constexpr float LOG2E    = 1.4426950408889634f;
static constexpr float QSCALE   = SM_SCALE * LOG2E;   // folded into q at projection

typedef short s16x8 __attribute__((ext_vector_type(8)));
typedef short s16x4 __attribute__((ext_vector_type(4)));
typedef float f32x4 __attribute__((ext_vector_type(4)));
typedef int   i32x4 __attribute__((ext_vector_type(4)));

__device__ __forceinline__ unsigned short f2bf(float f) {
    unsigned int u = __float_as_uint(f);
    u += 0x7fffu + ((u >> 16) & 1u);   // round-to-nearest-even
    return (unsigned short)(u >> 16);
}
__device__ __forceinline__ s16x8 ld8(const unsigned short* p) {
    return *(const s16x8*)p;           // 16B global_load_dwordx4 (bf16 x8)
}
// async global->LDS, 16B per lane
__device__ __forceinline__ void gld_lds16(const unsigned short* g, unsigned short* l) {
    __builtin_amdgcn_global_load_lds(
        (const __attribute__((address_space(1))) void*)g,
        (__attribute__((address_space(3))) void*)l, 16, 0, 0);
}
// pack two f32 -> one u32 of 2x bf16 (RNE); no builtin on gfx950
__device__ __forceinline__ unsigned int cvtpk(float lo, float hi) {
    unsigned int r;
    asm("v_cvt_pk_bf16_f32 %0, %1, %2" : "=v"(r) : "v"(lo), "v"(hi));
    return r;
}

#define BAR()     asm volatile("s_barrier" ::: "memory")
#define WAITVM8() asm volatile("s_waitcnt vmcnt(8)" ::: "memory")
#define WAITVM4() asm volatile("s_waitcnt vmcnt(4)" ::: "memory")
#define WAITVM0() asm volatile("s_waitcnt vmcnt(0)" ::: "memory")

// ---------------------------------------------------------------------------
// One-shot prep: x -> bf16 (blocks 0..4095), W's -> bf16 (blocks 4096..8191),
// qkv bias pack fp32 (blocks 8192+).
// ---------------------------------------------------------------------------
__global__ __launch_bounds__(256) void cast_all(
    const float* __restrict__ x,
    const float* __restrict__ Wq, const float* __restrict__ Wk,
    const float* __restrict__ Wv, const float* __restrict__ Wp,
    const float* __restrict__ bq, const float* __restrict__ bk,
    const float* __restrict__ bvv,
    unsigned short* __restrict__ xb, unsigned short* __restrict__ wall,
    float* __restrict__ ball)
{
    const int bid = blockIdx.x, tid = threadIdx.x;
    if (bid < 4096) {
        int i = bid * 256 + tid;                 // x: 1M float4
        float4 f = ((const float4*)x)[i];
        s16x4 o;
        o[0] = (short)f2bf(f.x); o[1] = (short)f2bf(f.y);
        o[2] = (short)f2bf(f.z); o[3] = (short)f2bf(f.w);
        ((s16x4*)xb)[i] = o;
    } else if (bid < 8192) {
        int j = (bid - 4096) * 256 + tid;        // W: 1M float4 over 4 mats
        int r = j >> 18;                         // 256K float4 per matrix
        const float* src = (r == 0) ? Wq : (r == 1) ? Wk : (r == 2) ? Wv : Wp;
        float4 f = ((const float4*)src)[j & 262143];
        s16x4 o;
        o[0] = (short)f2bf(f.x); o[1] = (short)f2bf(f.y);
        o[2] = (short)f2bf(f.z); o[3] = (short)f2bf(f.w);
        ((s16x4*)wall)[j] = o;
    } else {
        int t2 = (bid - 8192) * 256 + tid;
        if (t2 < 3072)
            ball[t2] = (t2 < 1024) ? bq[t2]
                     : (t2 < 2048) ? bk[t2 - 1024] : bvv[t2 - 2048];
    }
}

// ---------------------------------------------------------------------------
// 128x128-tile NT GEMM, K=1024, BK=32, 256 threads.
// R16: 3-deep circular LDS pipeline (48 KB, still 3 blocks/CU), prefetch
// distance 2, steady-state s_waitcnt vmcnt(8) (12 loads in flight; the wait
// confirms a buffer staged TWO compute phases earlier ~= HBM latency cover).
// WAR safety: s_barrier globally separates windows; stage(s+2) and
// compute(s) touch different slots ((s+2)%3 != s%3).
// R4 post-mortem: distance-1 dbuf was NEUTRAL (56.3->57.0) -> per-iter stall
// is HBM-miss latency (~900cy) that one ~300cy compute phase can't cover.
// XCD-pinned nt-chunks (nt_total % 8 == 0 for both call sites).
// mode 0 (QKV fused, N=3072): nt 0..7 -> q (scaled by QSCALE), 8..15 -> k,
//   16..23 -> v^T into vtb (b,h,d,l).  bias[proj*1024 + col].
// mode 1 (out-proj, N=1024): fp32 store to outf, bias[col].
// ---------------------------------------------------------------------------
__global__ __launch_bounds__(256) void gemm_tile(
    const unsigned short* __restrict__ A, int astride,
    const unsigned short* __restrict__ Wb,
    const float* __restrict__ bias,
    unsigned short* qk, unsigned short* vtb, float* outf, int mode)
{
    __shared__ __align__(16) unsigned short Asm[3][128 * 32];   // 3x8 KB
    __shared__ __align__(16) unsigned short Bsm[3][128 * 32];   // 3x8 KB

    const int t    = threadIdx.x;
    const int lane = t & 63;
    const int l15  = lane & 15;
    const int quad = lane >> 4;
    const int w    = t >> 6;
    const int mrow = (w & 1) * 64;
    const int ncol = (w >> 1) * 64;
    // XCD-pinned mapping: bid = i2*8 + xcd; nt chunked per XCD (bijective,
    // requires gridDim.x/32 % 8 == 0 -- holds for 24 and 8).
    const int nt_total = (int)gridDim.x >> 5;
    const int xcd = blockIdx.x & 7;
    const int i2  = blockIdx.x >> 3;
    const int nt  = xcd * (nt_total >> 3) + (i2 >> 5);
    const int mt  = i2 & 31;
    const int row0 = mt * 128;

    const unsigned short* ga = A  + (size_t)(row0 + (t >> 2)) * astride + (t & 3) * 8;
    const unsigned short* gb = Wb + (size_t)(nt * 128 + (t >> 2)) * DIMC + (t & 3) * 8;
    const size_t gaStep = (size_t)64 * astride;
    const size_t gbStep = (size_t)64 * DIMC;

    f32x4 acc[4][4] = {};

    // stage one BK=32 step (A+B halves) into buffer pair; 4 loads per thread
    auto stage = [&](unsigned short* Ab, unsigned short* Bb, int k0) {
        gld_lds16(ga + k0,          Ab + t * 8);
        gld_lds16(ga + gaStep + k0, Ab + 2048 + t * 8);
        gld_lds16(gb + k0,          Bb + t * 8);
        gld_lds16(gb + gbStep + k0, Bb + 2048 + t * 8);
    };

    // consume one staged step (compile-time buffer pointers)
    auto compute = [&](const unsigned short* Ac, const unsigned short* Bc) {
        s16x8 a[4], b[4];
#pragma unroll
        for (int mi = 0; mi < 4; ++mi)
            a[mi] = *(const s16x8*)(Ac + (mrow + mi * 16 + l15) * 32 + quad * 8);
#pragma unroll
        for (int ni = 0; ni < 4; ++ni)
            b[ni] = *(const s16x8*)(Bc + (ncol + ni * 16 + l15) * 32 + quad * 8);
        __builtin_amdgcn_s_setprio(1);
#pragma unroll
        for (int mi = 0; mi < 4; ++mi)
#pragma unroll
            for (int ni = 0; ni < 4; ++ni)
                acc[mi][ni] = __builtin_amdgcn_mfma_f32_16x16x32_bf16(
                    a[mi], b[ni], acc[mi][ni], 0, 0, 0);
        __builtin_amdgcn_s_setprio(0);
    };

    // prologue: stage k-steps 0 and 1 (8 loads in flight)
    stage(Asm[0], Bsm[0], 0);
    stage(Asm[1], Bsm[1], 32);

    // main loop: 10 outers x 3 steps = steps 0..29; stages cover steps 2..31.
    // Steady state: after stage(s+2) there are 12 loads in flight {s,s+1,s+2};
    // vmcnt(8) retires stage(s) (issued 2 compute phases ago).
#pragma unroll 1
    for (int k0 = 0; k0 < 960; k0 += 96) {
        stage(Asm[2], Bsm[2], k0 + 64);   // step s+2 -> slot (s+2)%3
        WAITVM8();
        BAR();
        compute(Asm[0], Bsm[0]);          // step s   -> slot s%3
        BAR();
        stage(Asm[0], Bsm[0], k0 + 96);
        WAITVM8();
        BAR();
        compute(Asm[1], Bsm[1]);
        BAR();
        stage(Asm[1], Bsm[1], k0 + 128);
        WAITVM8();
        BAR();
        compute(Asm[2], Bsm[2]);
        BAR();
    }
    // drain tail: steps 30 (slot 0) and 31 (slot 1)
    WAITVM4();
    BAR();
    compute(Asm[0], Bsm[0]);
    BAR();
    WAITVM0();
    BAR();
    compute(Asm[1], Bsm[1]);

    const int proj = nt >> 3;                  // mode0: 0=q 1=k 2=v ; mode1: 0
#pragma unroll
    for (int ni = 0; ni < 4; ++ni) {
        const int cq = (nt & 7) * 128 + ncol + ni * 16 + l15;   // col within proj
        const float bz = bias[proj * 1024 + cq];
#pragma unroll
        for (int mi = 0; mi < 4; ++mi) {
            const int rbase = row0 + mrow + mi * 16 + quad * 4;
            if (mode == 0) {
                if (proj < 2) {
                    const float scale = (proj == 0) ? QSCALE : 1.0f;
#pragma unroll
                    for (int r = 0; r < 4; ++r)
                        qk[(size_t)(rbase + r) * XSTR + proj * DIMC + cq] =
                            f2bf((acc[mi][ni][r] + bz) * scale);
                } else {
                    const int h = cq >> 6, d = cq & 63;
                    const int bb = rbase >> 11, ll = rbase & (SEQL - 1);
                    s16x4 v4;
                    v4[0] = (short)f2bf(acc[mi][ni][0] + bz);
                    v4[1] = (short)f2bf(acc[mi][ni][1] + bz);
                    v4[2] = (short)f2bf(acc[mi][ni][2] + bz);
                    v4[3] = (short)f2bf(acc[mi][ni][3] + bz);
                    *(s16x4*)(vtb + ((size_t)((bb * NH + h) * HD + d)) * SEQL + ll) = v4;
                }
            } else {
#pragma unroll
                for (int r = 0; r < 4; ++r)
                    outf[(size_t)(rbase + r) * DIMC + cq] = acc[mi][ni][r] + bz;
            }
        }
    }
}

// ---------------------------------------------------------------------------
// Flash attention v9 (verified R15/R16 bench): 256-thr blocks, 4 waves,
// 128 q-rows share one K/V staging; unroll-2 double buffer + raw s_barrier +
// counted vmcnt(4); s_setprio(1) around the MFMA/softmax cluster; l via
// all-ones-B MFMA; P-pack via v_cvt_pk_bf16_f32. UNCHANGED.
// ---------------------------------------------------------------------------
__global__ __launch_bounds__(256) void attn_fused(
    unsigned short* xqk,
    const unsigned short* __restrict__ vt)
{
    __shared__ __align__(16) unsigned short Ksm[2][64 * 64];   // 2x8 KB [key][d] swizzled
    __shared__ __align__(16) unsigned short Vsm[2][64 * 64];   // 2x8 KB [d][key] swizzled

    const int t    = threadIdx.x;
    const int lane = t & 63;
    const int l15  = lane & 15;
    const int quad = lane >> 4;
    const int w    = t >> 6;                 // wave 0..3

    // XCD-pinned mapping (bijective: bid = ii*8 + xcd), 512 blocks
    const int xcd = blockIdx.x & 7;
    const int ii  = blockIdx.x >> 3;         // 0..63
    const int bh  = (xcd << 2) | (ii >> 4);  // all 16 q-blocks of a bh on one XCD
    const int qb  = ii & 15;                 // 128-row q-block
    const int h  = bh & (NH - 1);
    const int bb = bh >> 4;
    const int q0A = qb * 128 + w * 16;       // wave's two q-tiles
    const int q0B = q0A + 64;

    // Q B-frags (lane&15 = q row), loaded before any O store (in-place safe)
    unsigned short* qbase = xqk + (size_t)(bb * SEQL) * XSTR + h * HD + quad * 8;
    unsigned short* qrA = qbase + (size_t)(q0A + l15) * XSTR;
    unsigned short* qrB = qbase + (size_t)(q0B + l15) * XSTR;
    const s16x8 bqA0 = ld8(qrA), bqA1 = ld8(qrA + 32);
    const s16x8 bqB0 = ld8(qrB), bqB1 = ld8(qrB + 32);

    // all-ones bf16 B-frag for the l-accumulation MFMA
    s16x8 bones;
#pragma unroll
    for (int e = 0; e < 8; ++e) bones[e] = (short)0x3F80;

    // staging: 256 threads cover a 64x64 tile in 2 row-groups of 32.
    // thread t: row-in-group tr = t>>3 (0..31), chunk pos tp = t&7; source
    // chunk XOR-swizzled so LDS pos p of row r holds logical chunk p^(r&7)
    // (r = tr + g*32; r&7 == tr&7 since 32 = 0 mod 8).
    const int tr = t >> 3, tp = t & 7;
    const int swz = (tp ^ (tr & 7)) * 8;
    const unsigned short* kg = xqk + (size_t)bb * SEQL * XSTR + DIMC + h * HD
                               + (size_t)tr * XSTR + swz;
    const unsigned short* vg = vt + (size_t)(bh * HD + tr) * SEQL + swz;

    f32x4 oA[4] = {}, oB[4] = {};
    f32x4 laccA = {}, laccB = {};            // row-sums of P (denominators)
    const int xk = l15 & 7;

    // stage one 64-key tile (K + V) into buffer buf; 4 loads per thread
    auto stage = [&](unsigned short* Kb, unsigned short* Vb, int j) {
#pragma unroll
        for (int g = 0; g < 2; ++g) {
            gld_lds16(kg + (size_t)(j + g * 32) * XSTR, Kb + g * 2048 + t * 8);
            gld_lds16(vg + (size_t)(g * 32) * SEQL + j,  Vb + g * 2048 + t * 8);
        }
    };

    // compute one 64-key tile from buffers (compile-time pointers)
    auto compute = [&](const unsigned short* Kc, const unsigned short* Vc) {
#pragma unroll
        for (int hf = 0; hf < 2; ++hf) {
            // K A-frags for two 16-key sub-blocks (shared by both q-tiles)
            const int k0 = (hf * 32 + l15) * 64;
            const int k1 = (hf * 32 + 16 + l15) * 64;
            s16x8 a00 = *(const s16x8*)(Kc + k0 + ((quad       ^ xk) * 8));
            s16x8 a01 = *(const s16x8*)(Kc + k0 + (((quad + 4) ^ xk) * 8));
            s16x8 a10 = *(const s16x8*)(Kc + k1 + ((quad       ^ xk) * 8));
            s16x8 a11 = *(const s16x8*)(Kc + k1 + (((quad + 4) ^ xk) * 8));

            // V B-frags with the key permutation (shared by both q-tiles)
            s16x8 bv[4];
#pragma unroll
            for (int c = 0; c < 4; ++c) {
                const unsigned short* va = Vc + (c * 16 + l15) * 64 + (quad & 1) * 4;
                const int kc0 = hf * 4 + (quad >> 1);
                s16x4 v0 = *(const s16x4*)(va + ((kc0       ^ xk) * 8));
                s16x4 v1 = *(const s16x4*)(va + (((kc0 + 2) ^ xk) * 8));
                bv[c] = __builtin_shufflevector(v0, v1, 0, 1, 2, 3, 4, 5, 6, 7);
            }

            __builtin_amdgcn_s_setprio(1);
            // q-tile A
            {
                f32x4 st0 = {}, st1 = {};
                st0 = __builtin_amdgcn_mfma_f32_16x16x32_bf16(a00, bqA0, st0, 0, 0, 0);
                st0 = __builtin_amdgcn_mfma_f32_16x16x32_bf16(a01, bqA1, st0, 0, 0, 0);
                st1 = __builtin_amdgcn_mfma_f32_16x16x32_bf16(a10, bqA0, st1, 0, 0, 0);
                st1 = __builtin_amdgcn_mfma_f32_16x16x32_bf16(a11, bqA1, st1, 0, 0, 0);
                i32x4 api;
                api[0] = (int)cvtpk(__builtin_amdgcn_exp2f(st0[0]),
                                    __builtin_amdgcn_exp2f(st0[1]));
                api[1] = (int)cvtpk(__builtin_amdgcn_exp2f(st0[2]),
                                    __builtin_amdgcn_exp2f(st0[3]));
                api[2] = (int)cvtpk(__builtin_amdgcn_exp2f(st1[0]),
                                    __builtin_amdgcn_exp2f(st1[1]));
                api[3] = (int)cvtpk(__builtin_amdgcn_exp2f(st1[2]),
                                    __builtin_amdgcn_exp2f(st1[3]));
                s16x8 ap = __builtin_bit_cast(s16x8, api);
                laccA = __builtin_amdgcn_mfma_f32_16x16x32_bf16(ap, bones, laccA, 0, 0, 0);
#pragma unroll
                for (int c = 0; c < 4; ++c)
                    oA[c] = __builtin_amdgcn_mfma_f32_16x16x32_bf16(ap, bv[c], oA[c], 0, 0, 0);
            }
            // q-tile B
            {
                f32x4 st0 = {}, st1 = {};
                st0 = __builtin_amdgcn_mfma_f32_16x16x32_bf16(a00, bqB0, st0, 0, 0, 0);
                st0 = __builtin_amdgcn_mfma_f32_16x16x32_bf16(a01, bqB1, st0, 0, 0, 0);
                st1 = __builtin_amdgcn_mfma_f32_16x16x32_bf16(a10, bqB0, st1, 0, 0, 0);
                st1 = __builtin_amdgcn_mfma_f32_16x16x32_bf16(a11, bqB1, st1, 0, 0, 0);
                i32x4 api;
                api[0] = (int)cvtpk(__builtin_amdgcn_exp2f(st0[0]),
                                    __builtin_amdgcn_exp2f(st0[1]));
                api[1] = (int)cvtpk(__builtin_amdgcn_exp2f(st0[2]),
                                    __builtin_amdgcn_exp2f(st0[3]));
                api[2] = (int)cvtpk(__builtin_amdgcn_exp2f(st1[0]),
                                    __builtin_amdgcn_exp2f(st1[1]));
                api[3] = (int)cvtpk(__builtin_amdgcn_exp2f(st1[2]),
                                    __builtin_amdgcn_exp2f(st1[3]));
                s16x8 ap = __builtin_bit_cast(s16x8, api);
                laccB = __builtin_amdgcn_mfma_f32_16x16x32_bf16(ap, bones, laccB, 0, 0, 0);
#pragma unroll
                for (int c = 0; c < 4; ++c)
                    oB[c] = __builtin_amdgcn_mfma_f32_16x16x32_bf16(ap, bv[c], oB[c], 0, 0, 0);
            }
            __builtin_amdgcn_s_setprio(0);
        }
    };

    // prologue: stage tile 0 into buffer 0
    stage(Ksm[0], Vsm[0], 0);

    // main loop: unroll-2 so buffer pointers are compile-time constants.
#pragma unroll 1
    for (int jt = 0; jt < SEQL / 64; jt += 2) {
        const int j0 = jt * 64;
        // body A: prefetch tile jt+1 -> buf1, compute buf0 (tile jt)
        stage(Ksm[1], Vsm[1], j0 + 64);
        WAITVM4();
        BAR();
        compute(Ksm[0], Vsm[0]);
        BAR();
        // body B: prefetch tile jt+2 -> buf0, compute buf1 (tile jt+1)
        if (jt + 2 < SEQL / 64) {
            stage(Ksm[0], Vsm[0], j0 + 128);
            WAITVM4();
        } else {
            WAITVM0();
        }
        BAR();
        compute(Ksm[1], Vsm[1]);
        BAR();
    }

    // laccX[r] = l for q-row quad*4+r (replicated across l15) -> no shuffles
    float liA[4], liB[4];
#pragma unroll
    for (int r = 0; r < 4; ++r) {
        liA[r] = 1.0f / laccA[r];
        liB[r] = 1.0f / laccB[r];
    }

#pragma unroll
    for (int c = 0; c < 4; ++c) {
        const int d = c * 16 + l15;
#pragma unroll
        for (int r = 0; r < 4; ++r) {
            const int qr = quad * 4 + r;
            xqk[(size_t)(bb * SEQL + q0A + qr) * XSTR + h * HD + d] = f2bf(oA[c][r] * liA[r]);
            xqk[(size_t)(bb * SEQL + q0B + qr) * XSTR + h * HD + d] = f2bf(oB[c][r] * liB[r]);
        }
    }
}

// ---------------------------------------------------------------------------
// ws layout (u16 elems): xb [0,4M) | Wq|Wk|Wv|Wp [4M,8M) | bias fp32 @ 8M.
// q (pre-scaled by 0.125*log2e), k -> x's buffer; V^T -> d_out (dead before
// out-proj); attn-out in-place over q slots; final fp32 out -> d_out.
// ---------------------------------------------------------------------------
extern "C" void kernel_launch(void* const* d_in, const int* in_sizes, int n_in,
                              void* d_out, int out_size, void* d_ws, size_t ws_size,
                              hipStream_t stream) {
    const float* x  = (const float*)d_in[0];
    const float* Wq = (const float*)d_in[1];
    const float* bq = (const float*)d_in[2];
    const float* Wk = (const float*)d_in[3];
    const float* bk = (const float*)d_in[4];
    const float* Wv = (const float*)d_in[5];
    const float* bv = (const float*)d_in[6];
    const float* Wp = (const float*)d_in[7];
    const float* bp = (const float*)d_in[8];
    float* out = (float*)d_out;
    unsigned short* vtb = (unsigned short*)d_out;
    unsigned short* xqk = (unsigned short*)d_in[0];

    unsigned short* ws   = (unsigned short*)d_ws;
    const size_t XELT = (size_t)MTOT * DIMC;     // 4M
    const size_t WELT = (size_t)DIMC * DIMC;     // 1M
    unsigned short* xb   = ws;
    unsigned short* wall = ws + XELT;
    float*          ball = (float*)(ws + 2 * XELT);

    cast_all<<<8204, 256, 0, stream>>>(x, Wq, Wk, Wv, Wp, bq, bk, bv, xb, wall, ball);

    // fused QKV GEMM: M=4096, N=3072 -> 32 x 24 tiles = 768 blocks
    gemm_tile<<<768, 256, 0, stream>>>(xb, DIMC, wall, ball, xqk, vtb, nullptr, 0);

    // attention: 512 blocks (32 bh x 16 q-blocks of 128 rows), 4 waves each
    attn_fused<<<NB * NH * (SEQL / 128), 256, 0, stream>>>(xqk, vtb);

    // out-proj: M=4096, N=1024 -> 256 blocks, fp32 out
    gemm_tile<<<256, 256, 0, stream>>>(xqk, XSTR, wall + 3 * WELT, bp,
                                       nullptr, nullptr, out, 1);
}

// Round 6
// 200.310 us; speedup vs baseline: 1.0750x; 1.0605x over previous
//
#include <hip/hip_runtime.h>

// Problem constants
#define DIMC 1024
#define SEQL 2048
#define NB   2
#define NH   16
#define HD   64
#define MTOT (NB*SEQL)          // 4096 rows
#define XSTR 2048               // q/k interleaved in x buffer: [q 1024 | k 1024] per row
static constexpr float SM_SCALE = 0.125f;             // HEAD_DIM^-0.5
static constexpr float LOG2E    = 1.4426950408889634f;
static constexpr float QSCALE   = SM_SCALE * LOG2E;   // folded into q at projection

typedef short s16x8 __attribute__((ext_vector_type(8)));
typedef short s16x4 __attribute__((ext_vector_type(4)));
typedef float f32x4 __attribute__((ext_vector_type(4)));
typedef int   i32x4 __attribute__((ext_vector_type(4)));

__device__ __forceinline__ unsigned short f2bf(float f) {
    unsigned int u = __float_as_uint(f);
    u += 0x7fffu + ((u >> 16) & 1u);   // round-to-nearest-even
    return (unsigned short)(u >> 16);
}
__device__ __forceinline__ s16x8 ld8(const unsigned short* p) {
    return *(const s16x8*)p;           // 16B global_load_dwordx4 (bf16 x8)
}
// async global->LDS, 16B per lane
__device__ __forceinline__ void gld_lds16(const unsigned short* g, unsigned short* l) {
    __builtin_amdgcn_global_load_lds(
        (const __attribute__((address_space(1))) void*)g,
        (__attribute__((address_space(3))) void*)l, 16, 0, 0);
}
// pack two f32 -> one u32 of 2x bf16 (RNE); no builtin on gfx950
__device__ __forceinline__ unsigned int cvtpk(float lo, float hi) {
    unsigned int r;
    asm("v_cvt_pk_bf16_f32 %0, %1, %2" : "=v"(r) : "v"(lo), "v"(hi));
    return r;
}

#define BAR()     asm volatile("s_barrier" ::: "memory")
#define WAITVM8() asm volatile("s_waitcnt vmcnt(8)" ::: "memory")
#define WAITVM4() asm volatile("s_waitcnt vmcnt(4)" ::: "memory")
#define WAITVM0() asm volatile("s_waitcnt vmcnt(0)" ::: "memory")

// ---------------------------------------------------------------------------
// One-shot prep: x -> bf16 (blocks 0..4095), W's -> bf16 (blocks 4096..8191),
// qkv bias pack fp32 (blocks 8192+).
// ---------------------------------------------------------------------------
__global__ __launch_bounds__(256) void cast_all(
    const float* __restrict__ x,
    const float* __restrict__ Wq, const float* __restrict__ Wk,
    const float* __restrict__ Wv, const float* __restrict__ Wp,
    const float* __restrict__ bq, const float* __restrict__ bk,
    const float* __restrict__ bvv,
    unsigned short* __restrict__ xb, unsigned short* __restrict__ wall,
    float* __restrict__ ball)
{
    const int bid = blockIdx.x, tid = threadIdx.x;
    if (bid < 4096) {
        int i = bid * 256 + tid;                 // x: 1M float4
        float4 f = ((const float4*)x)[i];
        s16x4 o;
        o[0] = (short)f2bf(f.x); o[1] = (short)f2bf(f.y);
        o[2] = (short)f2bf(f.z); o[3] = (short)f2bf(f.w);
        ((s16x4*)xb)[i] = o;
    } else if (bid < 8192) {
        int j = (bid - 4096) * 256 + tid;        // W: 1M float4 over 4 mats
        int r = j >> 18;                         // 256K float4 per matrix
        const float* src = (r == 0) ? Wq : (r == 1) ? Wk : (r == 2) ? Wv : Wp;
        float4 f = ((const float4*)src)[j & 262143];
        s16x4 o;
        o[0] = (short)f2bf(f.x); o[1] = (short)f2bf(f.y);
        o[2] = (short)f2bf(f.z); o[3] = (short)f2bf(f.w);
        ((s16x4*)wall)[j] = o;
    } else {
        int t2 = (bid - 8192) * 256 + tid;
        if (t2 < 3072)
            ball[t2] = (t2 < 1024) ? bq[t2]
                     : (t2 < 2048) ? bk[t2 - 1024] : bvv[t2 - 2048];
    }
}

// ---------------------------------------------------------------------------
// R17: 256x256-tile 8-phase QKV GEMM (m201/HK template ported). 512 thr,
// 8 waves (2M x 4N), BK=64, 128 KB dynamic LDS:
//   A: [buf][khalf][256 rows][32 cols] bf16 (4 x 16 KB), B same.
// Per K-tile: 4 phases {(ks0,mh0),(ks0,mh1),(ks1,mh0),(ks1,mh1)}, each:
//   12 ds_read_b128 (swizzled, conflict-free) | 1 staging unit (2 gld_lds)
//   | [vmcnt] | barrier | setprio(1) 16 MFMA setprio(0) | barrier.
// Unit issue order at tile T (buf b): ph1 T+1.Ak1->b^1, ph2 T+1.Bk1->b^1,
//   ph3 T+2.Ak0->b, ph4 T+2.Bk0->b.  Deadness: a region is overwritten only
//   after both phases reading it passed a barrier.  vmcnt(8) at ph2/ph4
//   retires exactly the unit needed two phases later (~6 phases of latency
//   cover); never drains to 0 mid-loop. Tail tiles peel to vmcnt(4)/(0).
// Swizzle: LDS chunk p of row r holds logical chunk p^((r>>1)&3); read addr
//   chunk = quad^((l15>>1)&3) -> 2 lanes/bank-slot (free). Staging applies
//   the same XOR to the GLOBAL source column (both-sides rule).
// FP K-order identical to the 128x128 kernel -> same rounding.
// ---------------------------------------------------------------------------
__global__ __launch_bounds__(512, 2) void qkv8(
    const unsigned short* __restrict__ A,     // xb, stride 1024
    const unsigned short* __restrict__ Wb,    // [Wq|Wk|Wv] rows
    const float* __restrict__ bias,
    unsigned short* __restrict__ qk, unsigned short* __restrict__ vtb)
{
    extern __shared__ __align__(16) unsigned short lds[];
    unsigned short* lA = lds;                 // 32768 elems (64 KB)
    unsigned short* lB = lds + 32768;         // 32768 elems (64 KB)

    const int t    = threadIdx.x;
    const int lane = t & 63;
    const int l15  = lane & 15;
    const int quad = lane >> 4;
    const int w    = t >> 6;                  // wave 0..7
    const int wm   = w >> 2;                  // 0..1 (M half)
    const int wn   = w & 3;                   // 0..3 (N quarter)

    // XCD-chunked bijective mapping: 192 blocks = 8 XCDs x 24
    const int xcd = blockIdx.x & 7;
    const int lb  = xcd * 24 + (blockIdx.x >> 3);   // 0..191, nt-major
    const int nt  = lb >> 4;                  // 0..11 (256-col panel)
    const int mt  = lb & 15;                  // 0..15 (256-row panel)
    const int row0 = mt * 256;

    // staging geometry: thread t covers row (t>>2) (+128 for 2nd issue),
    // LDS chunk c = t&3; global col pre-swizzled: logical = c ^ ((row>>1)&3)
    const int scol = (((t & 3) ^ ((t >> 3) & 3)) * 8);
    const unsigned short* gaQ = A  + (size_t)(row0 + (t >> 2)) * 1024 + scol;
    const unsigned short* gbQ = Wb + (size_t)(nt * 256 + (t >> 2)) * 1024 + scol;

    // read-side swizzle: chunk = quad ^ ((l15>>1)&3)
    const int xq = (quad ^ ((l15 >> 1) & 3)) * 8;

    f32x4 acc[8][4] = {};

    // stage unit: A or B, K-half ks of K-tile kt2, into buffer b (2 loads)
    auto stA = [&](int b, int ks, int kt2) {
        const unsigned short* s = gaQ + (size_t)kt2 * 64 + ks * 32;
        unsigned short* d = lA + (size_t)(b * 2 + ks) * 8192 + t * 8;
        gld_lds16(s, d);
        gld_lds16(s + (size_t)128 * 1024, d + 4096);
    };
    auto stB = [&](int b, int ks, int kt2) {
        const unsigned short* s = gbQ + (size_t)kt2 * 64 + ks * 32;
        unsigned short* d = lB + (size_t)(b * 2 + ks) * 8192 + t * 8;
        gld_lds16(s, d);
        gld_lds16(s + (size_t)128 * 1024, d + 4096);
    };

    // one phase: 12 ds_reads | issue | vmcnt | barrier | 16 MFMA | barrier
    auto doPhase = [&](const unsigned short* Ak, const unsigned short* Bk,
                       int mh, auto&& iss, int vm) {
        s16x8 fa[4], fb[4];
#pragma unroll
        for (int m = 0; m < 4; ++m)
            fa[m] = *(const s16x8*)(Ak + (wm * 128 + mh * 64 + m * 16 + l15) * 32 + xq);
#pragma unroll
        for (int n = 0; n < 4; ++n)
            fb[n] = *(const s16x8*)(Bk + (wn * 64 + n * 16 + l15) * 32 + xq);
        iss();
        if (vm == 8)      WAITVM8();
        else if (vm == 4) WAITVM4();
        else if (vm == 0) WAITVM0();
        BAR();
        __builtin_amdgcn_s_setprio(1);
#pragma unroll
        for (int m = 0; m < 4; ++m)
#pragma unroll
            for (int n = 0; n < 4; ++n)
                acc[mh * 4 + m][n] = __builtin_amdgcn_mfma_f32_16x16x32_bf16(
                    fa[m], fb[n], acc[mh * 4 + m][n], 0, 0, 0);
        __builtin_amdgcn_s_setprio(0);
        BAR();
    };

    // one K-tile = 4 phases. mode 0: steady; 1: tile 14; 2: tile 15 (tail)
    auto tile = [&](int b, int kt, int mode) {
        const unsigned short* Ak0 = lA + (size_t)b * 16384;
        const unsigned short* Bk0 = lB + (size_t)b * 16384;
        doPhase(Ak0, Bk0, 0, [&] { if (mode < 2) stA(b ^ 1, 1, kt + 1); }, -1);
        doPhase(Ak0, Bk0, 1, [&] { if (mode < 2) stB(b ^ 1, 1, kt + 1); },
                mode == 2 ? 0 : 8);
        doPhase(Ak0 + 8192, Bk0 + 8192, 0, [&] { if (mode == 0) stA(b, 0, kt + 2); }, -1);
        doPhase(Ak0 + 8192, Bk0 + 8192, 1, [&] { if (mode == 0) stB(b, 0, kt + 2); },
                mode == 0 ? 8 : (mode == 1 ? 4 : -1));
    };

    // prologue: tile0 all 4 units + tile1 Ak0,Bk0 (12 loads); retire tile0
    stA(0, 0, 0); stB(0, 0, 0);
    stA(0, 1, 0); stB(0, 1, 0);
    stA(1, 0, 1); stB(1, 0, 1);
    WAITVM4();
    BAR();

#pragma unroll 1
    for (int kt = 0; kt < 14; kt += 2) {
        tile(0, kt, 0);
        tile(1, kt + 1, 0);
    }
    tile(0, 14, 1);
    tile(1, 15, 2);

    // epilogue (same store paths as the 128^2 kernel)
    const int proj = nt >> 2;                  // 0=q 1=k 2=v
#pragma unroll
    for (int ni = 0; ni < 4; ++ni) {
        const int cq = (nt & 3) * 256 + wn * 64 + ni * 16 + l15;   // col in proj
        const float bz = bias[proj * 1024 + cq];
#pragma unroll
        for (int mi = 0; mi < 8; ++mi) {
            const int rbase = row0 + wm * 128 + mi * 16 + quad * 4;
            if (proj < 2) {
                const float scale = (proj == 0) ? QSCALE : 1.0f;
#pragma unroll
                for (int r = 0; r < 4; ++r)
                    qk[(size_t)(rbase + r) * XSTR + proj * DIMC + cq] =
                        f2bf((acc[mi][ni][r] + bz) * scale);
            } else {
                const int h = cq >> 6, d = cq & 63;
                const int bb2 = rbase >> 11, ll = rbase & (SEQL - 1);
                s16x4 v4;
                v4[0] = (short)f2bf(acc[mi][ni][0] + bz);
                v4[1] = (short)f2bf(acc[mi][ni][1] + bz);
                v4[2] = (short)f2bf(acc[mi][ni][2] + bz);
                v4[3] = (short)f2bf(acc[mi][ni][3] + bz);
                *(s16x4*)(vtb + ((size_t)((bb2 * NH + h) * HD + d)) * SEQL + ll) = v4;
            }
        }
    }
}

// ---------------------------------------------------------------------------
// 128x128-tile NT GEMM (R5 version, unchanged) -- now used for out-proj only.
// ---------------------------------------------------------------------------
__global__ __launch_bounds__(256) void gemm_tile(
    const unsigned short* __restrict__ A, int astride,
    const unsigned short* __restrict__ Wb,
    const float* __restrict__ bias,
    unsigned short* qk, unsigned short* vtb, float* outf, int mode)
{
    __shared__ __align__(16) unsigned short Asm[3][128 * 32];   // 3x8 KB
    __shared__ __align__(16) unsigned short Bsm[3][128 * 32];   // 3x8 KB

    const int t    = threadIdx.x;
    const int lane = t & 63;
    const int l15  = lane & 15;
    const int quad = lane >> 4;
    const int w    = t >> 6;
    const int mrow = (w & 1) * 64;
    const int ncol = (w >> 1) * 64;
    const int nt_total = (int)gridDim.x >> 5;
    const int xcd = blockIdx.x & 7;
    const int i2  = blockIdx.x >> 3;
    const int nt  = xcd * (nt_total >> 3) + (i2 >> 5);
    const int mt  = i2 & 31;
    const int row0 = mt * 128;

    const unsigned short* ga = A  + (size_t)(row0 + (t >> 2)) * astride + (t & 3) * 8;
    const unsigned short* gb = Wb + (size_t)(nt * 128 + (t >> 2)) * DIMC + (t & 3) * 8;
    const size_t gaStep = (size_t)64 * astride;
    const size_t gbStep = (size_t)64 * DIMC;

    f32x4 acc[4][4] = {};

    auto stage = [&](unsigned short* Ab, unsigned short* Bb, int k0) {
        gld_lds16(ga + k0,          Ab + t * 8);
        gld_lds16(ga + gaStep + k0, Ab + 2048 + t * 8);
        gld_lds16(gb + k0,          Bb + t * 8);
        gld_lds16(gb + gbStep + k0, Bb + 2048 + t * 8);
    };

    auto compute = [&](const unsigned short* Ac, const unsigned short* Bc) {
        s16x8 a[4], b[4];
#pragma unroll
        for (int mi = 0; mi < 4; ++mi)
            a[mi] = *(const s16x8*)(Ac + (mrow + mi * 16 + l15) * 32 + quad * 8);
#pragma unroll
        for (int ni = 0; ni < 4; ++ni)
            b[ni] = *(const s16x8*)(Bc + (ncol + ni * 16 + l15) * 32 + quad * 8);
        __builtin_amdgcn_s_setprio(1);
#pragma unroll
        for (int mi = 0; mi < 4; ++mi)
#pragma unroll
            for (int ni = 0; ni < 4; ++ni)
                acc[mi][ni] = __builtin_amdgcn_mfma_f32_16x16x32_bf16(
                    a[mi], b[ni], acc[mi][ni], 0, 0, 0);
        __builtin_amdgcn_s_setprio(0);
    };

    stage(Asm[0], Bsm[0], 0);
    stage(Asm[1], Bsm[1], 32);

#pragma unroll 1
    for (int k0 = 0; k0 < 960; k0 += 96) {
        stage(Asm[2], Bsm[2], k0 + 64);
        WAITVM8();
        BAR();
        compute(Asm[0], Bsm[0]);
        BAR();
        stage(Asm[0], Bsm[0], k0 + 96);
        WAITVM8();
        BAR();
        compute(Asm[1], Bsm[1]);
        BAR();
        stage(Asm[1], Bsm[1], k0 + 128);
        WAITVM8();
        BAR();
        compute(Asm[2], Bsm[2]);
        BAR();
    }
    WAITVM4();
    BAR();
    compute(Asm[0], Bsm[0]);
    BAR();
    WAITVM0();
    BAR();
    compute(Asm[1], Bsm[1]);

    const int proj = nt >> 3;
#pragma unroll
    for (int ni = 0; ni < 4; ++ni) {
        const int cq = (nt & 7) * 128 + ncol + ni * 16 + l15;
        const float bz = bias[proj * 1024 + cq];
#pragma unroll
        for (int mi = 0; mi < 4; ++mi) {
            const int rbase = row0 + mrow + mi * 16 + quad * 4;
            if (mode == 0) {
                if (proj < 2) {
                    const float scale = (proj == 0) ? QSCALE : 1.0f;
#pragma unroll
                    for (int r = 0; r < 4; ++r)
                        qk[(size_t)(rbase + r) * XSTR + proj * DIMC + cq] =
                            f2bf((acc[mi][ni][r] + bz) * scale);
                } else {
                    const int h = cq >> 6, d = cq & 63;
                    const int bb = rbase >> 11, ll = rbase & (SEQL - 1);
                    s16x4 v4;
                    v4[0] = (short)f2bf(acc[mi][ni][0] + bz);
                    v4[1] = (short)f2bf(acc[mi][ni][1] + bz);
                    v4[2] = (short)f2bf(acc[mi][ni][2] + bz);
                    v4[3] = (short)f2bf(acc[mi][ni][3] + bz);
                    *(s16x4*)(vtb + ((size_t)((bb * NH + h) * HD + d)) * SEQL + ll) = v4;
                }
            } else {
#pragma unroll
                for (int r = 0; r < 4; ++r)
                    outf[(size_t)(rbase + r) * DIMC + cq] = acc[mi][ni][r] + bz;
            }
        }
    }
}

// ---------------------------------------------------------------------------
// Flash attention v9 (verified R15/R16): UNCHANGED.
// ---------------------------------------------------------------------------
__global__ __launch_bounds__(256) void attn_fused(
    unsigned short* xqk,
    const unsigned short* __restrict__ vt)
{
    __shared__ __align__(16) unsigned short Ksm[2][64 * 64];   // 2x8 KB [key][d] swizzled
    __shared__ __align__(16) unsigned short Vsm[2][64 * 64];   // 2x8 KB [d][key] swizzled

    const int t    = threadIdx.x;
    const int lane = t & 63;
    const int l15  = lane & 15;
    const int quad = lane >> 4;
    const int w    = t >> 6;                 // wave 0..3

    const int xcd = blockIdx.x & 7;
    const int ii  = blockIdx.x >> 3;         // 0..63
    const int bh  = (xcd << 2) | (ii >> 4);
    const int qb  = ii & 15;                 // 128-row q-block
    const int h  = bh & (NH - 1);
    const int bb = bh >> 4;
    const int q0A = qb * 128 + w * 16;
    const int q0B = q0A + 64;

    unsigned short* qbase = xqk + (size_t)(bb * SEQL) * XSTR + h * HD + quad * 8;
    unsigned short* qrA = qbase + (size_t)(q0A + l15) * XSTR;
    unsigned short* qrB = qbase + (size_t)(q0B + l15) * XSTR;
    const s16x8 bqA0 = ld8(qrA), bqA1 = ld8(qrA + 32);
    const s16x8 bqB0 = ld8(qrB), bqB1 = ld8(qrB + 32);

    s16x8 bones;
#pragma unroll
    for (int e = 0; e < 8; ++e) bones[e] = (short)0x3F80;

    const int tr = t >> 3, tp = t & 7;
    const int swz = (tp ^ (tr & 7)) * 8;
    const unsigned short* kg = xqk + (size_t)bb * SEQL * XSTR + DIMC + h * HD
                               + (size_t)tr * XSTR + swz;
    const unsigned short* vg = vt + (size_t)(bh * HD + tr) * SEQL + swz;

    f32x4 oA[4] = {}, oB[4] = {};
    f32x4 laccA = {}, laccB = {};
    const int xk = l15 & 7;

    auto stage = [&](unsigned short* Kb, unsigned short* Vb, int j) {
#pragma unroll
        for (int g = 0; g < 2; ++g) {
            gld_lds16(kg + (size_t)(j + g * 32) * XSTR, Kb + g * 2048 + t * 8);
            gld_lds16(vg + (size_t)(g * 32) * SEQL + j,  Vb + g * 2048 + t * 8);
        }
    };

    auto compute = [&](const unsigned short* Kc, const unsigned short* Vc) {
#pragma unroll
        for (int hf = 0; hf < 2; ++hf) {
            const int k0 = (hf * 32 + l15) * 64;
            const int k1 = (hf * 32 + 16 + l15) * 64;
            s16x8 a00 = *(const s16x8*)(Kc + k0 + ((quad       ^ xk) * 8));
            s16x8 a01 = *(const s16x8*)(Kc + k0 + (((quad + 4) ^ xk) * 8));
            s16x8 a10 = *(const s16x8*)(Kc + k1 + ((quad       ^ xk) * 8));
            s16x8 a11 = *(const s16x8*)(Kc + k1 + (((quad + 4) ^ xk) * 8));

            s16x8 bv[4];
#pragma unroll
            for (int c = 0; c < 4; ++c) {
                const unsigned short* va = Vc + (c * 16 + l15) * 64 + (quad & 1) * 4;
                const int kc0 = hf * 4 + (quad >> 1);
                s16x4 v0 = *(const s16x4*)(va + ((kc0       ^ xk) * 8));
                s16x4 v1 = *(const s16x4*)(va + (((kc0 + 2) ^ xk) * 8));
                bv[c] = __builtin_shufflevector(v0, v1, 0, 1, 2, 3, 4, 5, 6, 7);
            }

            __builtin_amdgcn_s_setprio(1);
            {
                f32x4 st0 = {}, st1 = {};
                st0 = __builtin_amdgcn_mfma_f32_16x16x32_bf16(a00, bqA0, st0, 0, 0, 0);
                st0 = __builtin_amdgcn_mfma_f32_16x16x32_bf16(a01, bqA1, st0, 0, 0, 0);
                st1 = __builtin_amdgcn_mfma_f32_16x16x32_bf16(a10, bqA0, st1, 0, 0, 0);
                st1 = __builtin_amdgcn_mfma_f32_16x16x32_bf16(a11, bqA1, st1, 0, 0, 0);
                i32x4 api;
                api[0] = (int)cvtpk(__builtin_amdgcn_exp2f(st0[0]),
                                    __builtin_amdgcn_exp2f(st0[1]));
                api[1] = (int)cvtpk(__builtin_amdgcn_exp2f(st0[2]),
                                    __builtin_amdgcn_exp2f(st0[3]));
                api[2] = (int)cvtpk(__builtin_amdgcn_exp2f(st1[0]),
                                    __builtin_amdgcn_exp2f(st1[1]));
                api[3] = (int)cvtpk(__builtin_amdgcn_exp2f(st1[2]),
                                    __builtin_amdgcn_exp2f(st1[3]));
                s16x8 ap = __builtin_bit_cast(s16x8, api);
                laccA = __builtin_amdgcn_mfma_f32_16x16x32_bf16(ap, bones, laccA, 0, 0, 0);
#pragma unroll
                for (int c = 0; c < 4; ++c)
                    oA[c] = __builtin_amdgcn_mfma_f32_16x16x32_bf16(ap, bv[c], oA[c], 0, 0, 0);
            }
            {
                f32x4 st0 = {}, st1 = {};
                st0 = __builtin_amdgcn_mfma_f32_16x16x32_bf16(a00, bqB0, st0, 0, 0, 0);
                st0 = __builtin_amdgcn_mfma_f32_16x16x32_bf16(a01, bqB1, st0, 0, 0, 0);
                st1 = __builtin_amdgcn_mfma_f32_16x16x32_bf16(a10, bqB0, st1, 0, 0, 0);
                st1 = __builtin_amdgcn_mfma_f32_16x16x32_bf16(a11, bqB1, st1, 0, 0, 0);
                i32x4 api;
                api[0] = (int)cvtpk(__builtin_amdgcn_exp2f(st0[0]),
                                    __builtin_amdgcn_exp2f(st0[1]));
                api[1] = (int)cvtpk(__builtin_amdgcn_exp2f(st0[2]),
                                    __builtin_amdgcn_exp2f(st0[3]));
                api[2] = (int)cvtpk(__builtin_amdgcn_exp2f(st1[0]),
                                    __builtin_amdgcn_exp2f(st1[1]));
                api[3] = (int)cvtpk(__builtin_amdgcn_exp2f(st1[2]),
                                    __builtin_amdgcn_exp2f(st1[3]));
                s16x8 ap = __builtin_bit_cast(s16x8, api);
                laccB = __builtin_amdgcn_mfma_f32_16x16x32_bf16(ap, bones, laccB, 0, 0, 0);
#pragma unroll
                for (int c = 0; c < 4; ++c)
                    oB[c] = __builtin_amdgcn_mfma_f32_16x16x32_bf16(ap, bv[c], oB[c], 0, 0, 0);
            }
            __builtin_amdgcn_s_setprio(0);
        }
    };

    stage(Ksm[0], Vsm[0], 0);

#pragma unroll 1
    for (int jt = 0; jt < SEQL / 64; jt += 2) {
        const int j0 = jt * 64;
        stage(Ksm[1], Vsm[1], j0 + 64);
        WAITVM4();
        BAR();
        compute(Ksm[0], Vsm[0]);
        BAR();
        if (jt + 2 < SEQL / 64) {
            stage(Ksm[0], Vsm[0], j0 + 128);
            WAITVM4();
        } else {
            WAITVM0();
        }
        BAR();
        compute(Ksm[1], Vsm[1]);
        BAR();
    }

    float liA[4], liB[4];
#pragma unroll
    for (int r = 0; r < 4; ++r) {
        liA[r] = 1.0f / laccA[r];
        liB[r] = 1.0f / laccB[r];
    }

#pragma unroll
    for (int c = 0; c < 4; ++c) {
        const int d = c * 16 + l15;
#pragma unroll
        for (int r = 0; r < 4; ++r) {
            const int qr = quad * 4 + r;
            xqk[(size_t)(bb * SEQL + q0A + qr) * XSTR + h * HD + d] = f2bf(oA[c][r] * liA[r]);
            xqk[(size_t)(bb * SEQL + q0B + qr) * XSTR + h * HD + d] = f2bf(oB[c][r] * liB[r]);
        }
    }
}

// ---------------------------------------------------------------------------
// ws layout (u16 elems): xb [0,4M) | Wq|Wk|Wv|Wp [4M,8M) | bias fp32 @ 8M.
// ---------------------------------------------------------------------------
extern "C" void kernel_launch(void* const* d_in, const int* in_sizes, int n_in,
                              void* d_out, int out_size, void* d_ws, size_t ws_size,
                              hipStream_t stream) {
    const float* x  = (const float*)d_in[0];
    const float* Wq = (const float*)d_in[1];
    const float* bq = (const float*)d_in[2];
    const float* Wk = (const float*)d_in[3];
    const float* bk = (const float*)d_in[4];
    const float* Wv = (const float*)d_in[5];
    const float* bv = (const float*)d_in[6];
    const float* Wp = (const float*)d_in[7];
    const float* bp = (const float*)d_in[8];
    float* out = (float*)d_out;
    unsigned short* vtb = (unsigned short*)d_out;
    unsigned short* xqk = (unsigned short*)d_in[0];

    unsigned short* ws   = (unsigned short*)d_ws;
    const size_t XELT = (size_t)MTOT * DIMC;     // 4M
    const size_t WELT = (size_t)DIMC * DIMC;     // 1M
    unsigned short* xb   = ws;
    unsigned short* wall = ws + XELT;
    float*          ball = (float*)(ws + 2 * XELT);

    // allow 128 KB dynamic LDS for qkv8 (one-time; harmless if no-op on ROCm)
    static bool ldsInit = false;
    if (!ldsInit) {
        (void)hipFuncSetAttribute((const void*)qkv8,
                                  hipFuncAttributeMaxDynamicSharedMemorySize,
                                  131072);
        ldsInit = true;
    }

    cast_all<<<8204, 256, 0, stream>>>(x, Wq, Wk, Wv, Wp, bq, bk, bv, xb, wall, ball);

    // fused QKV GEMM: M=4096, N=3072 -> 16 x 12 tiles of 256^2 = 192 blocks
    qkv8<<<192, 512, 131072, stream>>>(xb, wall, ball, xqk, vtb);

    // attention: 512 blocks (32 bh x 16 q-blocks of 128 rows), 4 waves each
    attn_fused<<<NB * NH * (SEQL / 128), 256, 0, stream>>>(xqk, vtb);

    // out-proj: M=4096, N=1024 -> 256 blocks, fp32 out
    gemm_tile<<<256, 256, 0, stream>>>(xqk, XSTR, wall + 3 * WELT, bp,
                                       nullptr, nullptr, out, 1);
}

// Round 7
// 194.600 us; speedup vs baseline: 1.1065x; 1.0293x over previous
//
#include <hip/hip_runtime.h>

// Problem constants
#define DIMC 1024
#define SEQL 2048
#define NB   2
#define NH   16
#define HD   64
#define MTOT (NB*SEQL)          // 4096 rows
#define XSTR 2048               // q/k interleaved in x buffer: [q 1024 | k 1024] per row
static constexpr float SM_SCALE = 0.125f;             // HEAD_DIM^-0.5
static constexpr float LOG2E    = 1.4426950408889634f;
static constexpr float QSCALE   = SM_SCALE * LOG2E;   // folded into q at projection

typedef short s16x8 __attribute__((ext_vector_type(8)));
typedef short s16x4 __attribute__((ext_vector_type(4)));
typedef float f32x4 __attribute__((ext_vector_type(4)));
typedef int   i32x4 __attribute__((ext_vector_type(4)));

__device__ __forceinline__ unsigned short f2bf(float f) {
    unsigned int u = __float_as_uint(f);
    u += 0x7fffu + ((u >> 16) & 1u);   // round-to-nearest-even
    return (unsigned short)(u >> 16);
}
__device__ __forceinline__ s16x8 ld8(const unsigned short* p) {
    return *(const s16x8*)p;           // 16B global_load_dwordx4 (bf16 x8)
}
// async global->LDS, 16B per lane
__device__ __forceinline__ void gld_lds16(const unsigned short* g, unsigned short* l) {
    __builtin_amdgcn_global_load_lds(
        (const __attribute__((address_space(1))) void*)g,
        (__attribute__((address_space(3))) void*)l, 16, 0, 0);
}
// pack two f32 -> one u32 of 2x bf16 (RNE); no builtin on gfx950
__device__ __forceinline__ unsigned int cvtpk(float lo, float hi) {
    unsigned int r;
    asm("v_cvt_pk_bf16_f32 %0, %1, %2" : "=v"(r) : "v"(lo), "v"(hi));
    return r;
}

#define BAR()     asm volatile("s_barrier" ::: "memory")
#define WAITVM8() asm volatile("s_waitcnt vmcnt(8)" ::: "memory")
#define WAITVM4() asm volatile("s_waitcnt vmcnt(4)" ::: "memory")
#define WAITVM0() asm volatile("s_waitcnt vmcnt(0)" ::: "memory")

// ---------------------------------------------------------------------------
// One-shot prep: x -> bf16 (blocks 0..4095), W's -> bf16 (blocks 4096..8191),
// qkv bias pack fp32 (blocks 8192+).
// ---------------------------------------------------------------------------
__global__ __launch_bounds__(256) void cast_all(
    const float* __restrict__ x,
    const float* __restrict__ Wq, const float* __restrict__ Wk,
    const float* __restrict__ Wv, const float* __restrict__ Wp,
    const float* __restrict__ bq, const float* __restrict__ bk,
    const float* __restrict__ bvv,
    unsigned short* __restrict__ xb, unsigned short* __restrict__ wall,
    float* __restrict__ ball)
{
    const int bid = blockIdx.x, tid = threadIdx.x;
    if (bid < 4096) {
        int i = bid * 256 + tid;                 // x: 1M float4
        float4 f = ((const float4*)x)[i];
        s16x4 o;
        o[0] = (short)f2bf(f.x); o[1] = (short)f2bf(f.y);
        o[2] = (short)f2bf(f.z); o[3] = (short)f2bf(f.w);
        ((s16x4*)xb)[i] = o;
    } else if (bid < 8192) {
        int j = (bid - 4096) * 256 + tid;        // W: 1M float4 over 4 mats
        int r = j >> 18;                         // 256K float4 per matrix
        const float* src = (r == 0) ? Wq : (r == 1) ? Wk : (r == 2) ? Wv : Wp;
        float4 f = ((const float4*)src)[j & 262143];
        s16x4 o;
        o[0] = (short)f2bf(f.x); o[1] = (short)f2bf(f.y);
        o[2] = (short)f2bf(f.z); o[3] = (short)f2bf(f.w);
        ((s16x4*)wall)[j] = o;
    } else {
        int t2 = (bid - 8192) * 256 + tid;
        if (t2 < 3072)
            ball[t2] = (t2 < 1024) ? bq[t2]
                     : (t2 < 2048) ? bk[t2 - 1024] : bvv[t2 - 2048];
    }
}

// ---------------------------------------------------------------------------
// R18: 256x192-tile 8-phase QKV GEMM. R6 post-mortem: 256x256 -> 192 blocks
// = 0.75 CU fill (128 KB LDS forces 1 block/CU); BN=192 -> 16x16 = 256
// blocks = FULL fill. Schedule, swizzle, and vmcnt accounting are bit-
// identical to the verified R6 kernel (every unit = 2 loads/wave):
//   B-unit (192 rows x 32 cols = 6144 elems) staged as issue1 rows 0..127
//   (all threads) + issue2 rows 128..191 where threads 256..511 DUPLICATE
//   threads 0..255 (same src, same dest, same bytes - benign) so per-wave
//   outstanding-load counts stay uniform.
// Per K-tile: 4 phases, each: 7 ds_read_b128 | 1 unit issue | [vmcnt] |
//   barrier | setprio(1) 12 MFMA setprio(0) | barrier. vmcnt(8) at ph2/ph4.
// LDS 112 KB: A [buf][ks][256][32] 64 KB, B [buf][ks][192][32] 48 KB.
// Epilogue: global col cq in 0..3071; bias = ball[cq]; q/k (cq<2048) store
// qk[row*XSTR+cq]; v (cq>=2048) -> vtb (b,h,d,l) s16x4 along rows.
// ---------------------------------------------------------------------------
__global__ __launch_bounds__(512, 2) void qkv8(
    const unsigned short* __restrict__ A,     // xb, stride 1024
    const unsigned short* __restrict__ Wb,    // [Wq|Wk|Wv] rows
    const float* __restrict__ bias,
    unsigned short* __restrict__ qk, unsigned short* __restrict__ vtb)
{
    extern __shared__ __align__(16) unsigned short lds[];
    unsigned short* lA = lds;                 // 32768 elems (64 KB)
    unsigned short* lB = lds + 32768;         // 24576 elems (48 KB)

    const int t    = threadIdx.x;
    const int lane = t & 63;
    const int l15  = lane & 15;
    const int quad = lane >> 4;
    const int w    = t >> 6;                  // wave 0..7
    const int wm   = w >> 2;                  // 0..1 (M half)
    const int wn   = w & 3;                   // 0..3 (N quarter, 48 cols)

    // XCD-chunked bijective mapping: 256 blocks = 8 XCDs x 32
    const int xcd = blockIdx.x & 7;
    const int lb  = xcd * 32 + (blockIdx.x >> 3);   // 0..255, nt-major
    const int nt  = lb >> 4;                  // 0..15 (192-col panel)
    const int mt  = lb & 15;                  // 0..15 (256-row panel)
    const int row0 = mt * 256;

    // staging geometry: thread t covers row (t>>2), LDS chunk c = t&3;
    // global col pre-swizzled: logical chunk = c ^ ((row>>1)&3)
    const int scol = (((t & 3) ^ ((t >> 3) & 3)) * 8);
    const int u    = t & 255;                 // duplicate index for B issue2
    const unsigned short* gaQ  = A  + (size_t)(row0 + (t >> 2)) * 1024 + scol;
    const unsigned short* gbQ  = Wb + (size_t)(nt * 192 + (t >> 2)) * 1024 + scol;
    const unsigned short* gbQ2 = Wb + (size_t)(nt * 192 + 128 + (u >> 2)) * 1024
                                 + ((((u & 3) ^ ((u >> 3) & 3))) * 8);

    // read-side swizzle: chunk = quad ^ ((l15>>1)&3)
    const int xq = (quad ^ ((l15 >> 1) & 3)) * 8;

    f32x4 acc[8][3] = {};

    // stage unit: K-half ks of K-tile kt2 into buffer b (always 2 loads/wave)
    auto stA = [&](int b, int ks, int kt2) {
        const unsigned short* s = gaQ + (size_t)kt2 * 64 + ks * 32;
        unsigned short* d = lA + (size_t)(b * 2 + ks) * 8192 + t * 8;
        gld_lds16(s, d);
        gld_lds16(s + (size_t)128 * 1024, d + 4096);
    };
    auto stB = [&](int b, int ks, int kt2) {
        unsigned short* dbase = lB + (size_t)(b * 2 + ks) * 6144;
        gld_lds16(gbQ + (size_t)kt2 * 64 + ks * 32, dbase + t * 8);
        // rows 128..191; threads 256..511 duplicate 0..255 (uniform vmcnt)
        gld_lds16(gbQ2 + (size_t)kt2 * 64 + ks * 32, dbase + 4096 + u * 8);
    };

    // one phase: 7 ds_reads | issue | vmcnt | barrier | 12 MFMA | barrier
    auto doPhase = [&](const unsigned short* Ak, const unsigned short* Bk,
                       int mh, auto&& iss, int vm) {
        s16x8 fa[4], fb[3];
#pragma unroll
        for (int m = 0; m < 4; ++m)
            fa[m] = *(const s16x8*)(Ak + (wm * 128 + mh * 64 + m * 16 + l15) * 32 + xq);
#pragma unroll
        for (int n = 0; n < 3; ++n)
            fb[n] = *(const s16x8*)(Bk + (wn * 48 + n * 16 + l15) * 32 + xq);
        iss();
        if (vm == 8)      WAITVM8();
        else if (vm == 4) WAITVM4();
        else if (vm == 0) WAITVM0();
        BAR();
        __builtin_amdgcn_s_setprio(1);
#pragma unroll
        for (int m = 0; m < 4; ++m)
#pragma unroll
            for (int n = 0; n < 3; ++n)
                acc[mh * 4 + m][n] = __builtin_amdgcn_mfma_f32_16x16x32_bf16(
                    fa[m], fb[n], acc[mh * 4 + m][n], 0, 0, 0);
        __builtin_amdgcn_s_setprio(0);
        BAR();
    };

    // one K-tile = 4 phases. mode 0: steady; 1: tile 14; 2: tile 15 (tail)
    auto tile = [&](int b, int kt, int mode) {
        const unsigned short* Ak0 = lA + (size_t)b * 16384;
        const unsigned short* Bk0 = lB + (size_t)b * 12288;
        doPhase(Ak0, Bk0, 0, [&] { if (mode < 2) stA(b ^ 1, 1, kt + 1); }, -1);
        doPhase(Ak0, Bk0, 1, [&] { if (mode < 2) stB(b ^ 1, 1, kt + 1); },
                mode == 2 ? 0 : 8);
        doPhase(Ak0 + 8192, Bk0 + 6144, 0, [&] { if (mode == 0) stA(b, 0, kt + 2); }, -1);
        doPhase(Ak0 + 8192, Bk0 + 6144, 1, [&] { if (mode == 0) stB(b, 0, kt + 2); },
                mode == 0 ? 8 : (mode == 1 ? 4 : -1));
    };

    // prologue: tile0 all 4 units + tile1 Ak0,Bk0 (12 loads); retire tile0
    stA(0, 0, 0); stB(0, 0, 0);
    stA(0, 1, 0); stB(0, 1, 0);
    stA(1, 0, 1); stB(1, 0, 1);
    WAITVM4();
    BAR();

#pragma unroll 1
    for (int kt = 0; kt < 14; kt += 2) {
        tile(0, kt, 0);
        tile(1, kt + 1, 0);
    }
    tile(0, 14, 1);
    tile(1, 15, 2);

    // epilogue
#pragma unroll
    for (int ni = 0; ni < 3; ++ni) {
        const int cq = nt * 192 + wn * 48 + ni * 16 + l15;   // global col 0..3071
        const float bz = bias[cq];
#pragma unroll
        for (int mi = 0; mi < 8; ++mi) {
            const int rbase = row0 + wm * 128 + mi * 16 + quad * 4;
            if (cq < 2048) {                     // q or k (16-col frags never straddle)
                const float scale = (cq < 1024) ? QSCALE : 1.0f;
#pragma unroll
                for (int r = 0; r < 4; ++r)
                    qk[(size_t)(rbase + r) * XSTR + cq] =
                        f2bf((acc[mi][ni][r] + bz) * scale);
            } else {                             // v -> v^T (b,h,d,l)
                const int c2 = cq - 2048;
                const int h = c2 >> 6, d = c2 & 63;
                const int bb2 = rbase >> 11, ll = rbase & (SEQL - 1);
                s16x4 v4;
                v4[0] = (short)f2bf(acc[mi][ni][0] + bz);
                v4[1] = (short)f2bf(acc[mi][ni][1] + bz);
                v4[2] = (short)f2bf(acc[mi][ni][2] + bz);
                v4[3] = (short)f2bf(acc[mi][ni][3] + bz);
                *(s16x4*)(vtb + ((size_t)((bb2 * NH + h) * HD + d)) * SEQL + ll) = v4;
            }
        }
    }
}

// ---------------------------------------------------------------------------
// 128x128-tile NT GEMM (R5 version, unchanged) -- out-proj only.
// ---------------------------------------------------------------------------
__global__ __launch_bounds__(256) void gemm_tile(
    const unsigned short* __restrict__ A, int astride,
    const unsigned short* __restrict__ Wb,
    const float* __restrict__ bias,
    unsigned short* qk, unsigned short* vtb, float* outf, int mode)
{
    __shared__ __align__(16) unsigned short Asm[3][128 * 32];   // 3x8 KB
    __shared__ __align__(16) unsigned short Bsm[3][128 * 32];   // 3x8 KB

    const int t    = threadIdx.x;
    const int lane = t & 63;
    const int l15  = lane & 15;
    const int quad = lane >> 4;
    const int w    = t >> 6;
    const int mrow = (w & 1) * 64;
    const int ncol = (w >> 1) * 64;
    const int nt_total = (int)gridDim.x >> 5;
    const int xcd = blockIdx.x & 7;
    const int i2  = blockIdx.x >> 3;
    const int nt  = xcd * (nt_total >> 3) + (i2 >> 5);
    const int mt  = i2 & 31;
    const int row0 = mt * 128;

    const unsigned short* ga = A  + (size_t)(row0 + (t >> 2)) * astride + (t & 3) * 8;
    const unsigned short* gb = Wb + (size_t)(nt * 128 + (t >> 2)) * DIMC + (t & 3) * 8;
    const size_t gaStep = (size_t)64 * astride;
    const size_t gbStep = (size_t)64 * DIMC;

    f32x4 acc[4][4] = {};

    auto stage = [&](unsigned short* Ab, unsigned short* Bb, int k0) {
        gld_lds16(ga + k0,          Ab + t * 8);
        gld_lds16(ga + gaStep + k0, Ab + 2048 + t * 8);
        gld_lds16(gb + k0,          Bb + t * 8);
        gld_lds16(gb + gbStep + k0, Bb + 2048 + t * 8);
    };

    auto compute = [&](const unsigned short* Ac, const unsigned short* Bc) {
        s16x8 a[4], b[4];
#pragma unroll
        for (int mi = 0; mi < 4; ++mi)
            a[mi] = *(const s16x8*)(Ac + (mrow + mi * 16 + l15) * 32 + quad * 8);
#pragma unroll
        for (int ni = 0; ni < 4; ++ni)
            b[ni] = *(const s16x8*)(Bc + (ncol + ni * 16 + l15) * 32 + quad * 8);
        __builtin_amdgcn_s_setprio(1);
#pragma unroll
        for (int mi = 0; mi < 4; ++mi)
#pragma unroll
            for (int ni = 0; ni < 4; ++ni)
                acc[mi][ni] = __builtin_amdgcn_mfma_f32_16x16x32_bf16(
                    a[mi], b[ni], acc[mi][ni], 0, 0, 0);
        __builtin_amdgcn_s_setprio(0);
    };

    stage(Asm[0], Bsm[0], 0);
    stage(Asm[1], Bsm[1], 32);

#pragma unroll 1
    for (int k0 = 0; k0 < 960; k0 += 96) {
        stage(Asm[2], Bsm[2], k0 + 64);
        WAITVM8();
        BAR();
        compute(Asm[0], Bsm[0]);
        BAR();
        stage(Asm[0], Bsm[0], k0 + 96);
        WAITVM8();
        BAR();
        compute(Asm[1], Bsm[1]);
        BAR();
        stage(Asm[1], Bsm[1], k0 + 128);
        WAITVM8();
        BAR();
        compute(Asm[2], Bsm[2]);
        BAR();
    }
    WAITVM4();
    BAR();
    compute(Asm[0], Bsm[0]);
    BAR();
    WAITVM0();
    BAR();
    compute(Asm[1], Bsm[1]);

    const int proj = nt >> 3;
#pragma unroll
    for (int ni = 0; ni < 4; ++ni) {
        const int cq = (nt & 7) * 128 + ncol + ni * 16 + l15;
        const float bz = bias[proj * 1024 + cq];
#pragma unroll
        for (int mi = 0; mi < 4; ++mi) {
            const int rbase = row0 + mrow + mi * 16 + quad * 4;
            if (mode == 0) {
                if (proj < 2) {
                    const float scale = (proj == 0) ? QSCALE : 1.0f;
#pragma unroll
                    for (int r = 0; r < 4; ++r)
                        qk[(size_t)(rbase + r) * XSTR + proj * DIMC + cq] =
                            f2bf((acc[mi][ni][r] + bz) * scale);
                } else {
                    const int h = cq >> 6, d = cq & 63;
                    const int bb = rbase >> 11, ll = rbase & (SEQL - 1);
                    s16x4 v4;
                    v4[0] = (short)f2bf(acc[mi][ni][0] + bz);
                    v4[1] = (short)f2bf(acc[mi][ni][1] + bz);
                    v4[2] = (short)f2bf(acc[mi][ni][2] + bz);
                    v4[3] = (short)f2bf(acc[mi][ni][3] + bz);
                    *(s16x4*)(vtb + ((size_t)((bb * NH + h) * HD + d)) * SEQL + ll) = v4;
                }
            } else {
#pragma unroll
                for (int r = 0; r < 4; ++r)
                    outf[(size_t)(rbase + r) * DIMC + cq] = acc[mi][ni][r] + bz;
            }
        }
    }
}

// ---------------------------------------------------------------------------
// Flash attention v9 (verified R15/R16): UNCHANGED.
// ---------------------------------------------------------------------------
__global__ __launch_bounds__(256) void attn_fused(
    unsigned short* xqk,
    const unsigned short* __restrict__ vt)
{
    __shared__ __align__(16) unsigned short Ksm[2][64 * 64];   // 2x8 KB [key][d] swizzled
    __shared__ __align__(16) unsigned short Vsm[2][64 * 64];   // 2x8 KB [d][key] swizzled

    const int t    = threadIdx.x;
    const int lane = t & 63;
    const int l15  = lane & 15;
    const int quad = lane >> 4;
    const int w    = t >> 6;                 // wave 0..3

    const int xcd = blockIdx.x & 7;
    const int ii  = blockIdx.x >> 3;         // 0..63
    const int bh  = (xcd << 2) | (ii >> 4);
    const int qb  = ii & 15;                 // 128-row q-block
    const int h  = bh & (NH - 1);
    const int bb = bh >> 4;
    const int q0A = qb * 128 + w * 16;
    const int q0B = q0A + 64;

    unsigned short* qbase = xqk + (size_t)(bb * SEQL) * XSTR + h * HD + quad * 8;
    unsigned short* qrA = qbase + (size_t)(q0A + l15) * XSTR;
    unsigned short* qrB = qbase + (size_t)(q0B + l15) * XSTR;
    const s16x8 bqA0 = ld8(qrA), bqA1 = ld8(qrA + 32);
    const s16x8 bqB0 = ld8(qrB), bqB1 = ld8(qrB + 32);

    s16x8 bones;
#pragma unroll
    for (int e = 0; e < 8; ++e) bones[e] = (short)0x3F80;

    const int tr = t >> 3, tp = t & 7;
    const int swz = (tp ^ (tr & 7)) * 8;
    const unsigned short* kg = xqk + (size_t)bb * SEQL * XSTR + DIMC + h * HD
                               + (size_t)tr * XSTR + swz;
    const unsigned short* vg = vt + (size_t)(bh * HD + tr) * SEQL + swz;

    f32x4 oA[4] = {}, oB[4] = {};
    f32x4 laccA = {}, laccB = {};
    const int xk = l15 & 7;

    auto stage = [&](unsigned short* Kb, unsigned short* Vb, int j) {
#pragma unroll
        for (int g = 0; g < 2; ++g) {
            gld_lds16(kg + (size_t)(j + g * 32) * XSTR, Kb + g * 2048 + t * 8);
            gld_lds16(vg + (size_t)(g * 32) * SEQL + j,  Vb + g * 2048 + t * 8);
        }
    };

    auto compute = [&](const unsigned short* Kc, const unsigned short* Vc) {
#pragma unroll
        for (int hf = 0; hf < 2; ++hf) {
            const int k0 = (hf * 32 + l15) * 64;
            const int k1 = (hf * 32 + 16 + l15) * 64;
            s16x8 a00 = *(const s16x8*)(Kc + k0 + ((quad       ^ xk) * 8));
            s16x8 a01 = *(const s16x8*)(Kc + k0 + (((quad + 4) ^ xk) * 8));
            s16x8 a10 = *(const s16x8*)(Kc + k1 + ((quad       ^ xk) * 8));
            s16x8 a11 = *(const s16x8*)(Kc + k1 + (((quad + 4) ^ xk) * 8));

            s16x8 bv[4];
#pragma unroll
            for (int c = 0; c < 4; ++c) {
                const unsigned short* va = Vc + (c * 16 + l15) * 64 + (quad & 1) * 4;
                const int kc0 = hf * 4 + (quad >> 1);
                s16x4 v0 = *(const s16x4*)(va + ((kc0       ^ xk) * 8));
                s16x4 v1 = *(const s16x4*)(va + (((kc0 + 2) ^ xk) * 8));
                bv[c] = __builtin_shufflevector(v0, v1, 0, 1, 2, 3, 4, 5, 6, 7);
            }

            __builtin_amdgcn_s_setprio(1);
            {
                f32x4 st0 = {}, st1 = {};
                st0 = __builtin_amdgcn_mfma_f32_16x16x32_bf16(a00, bqA0, st0, 0, 0, 0);
                st0 = __builtin_amdgcn_mfma_f32_16x16x32_bf16(a01, bqA1, st0, 0, 0, 0);
                st1 = __builtin_amdgcn_mfma_f32_16x16x32_bf16(a10, bqA0, st1, 0, 0, 0);
                st1 = __builtin_amdgcn_mfma_f32_16x16x32_bf16(a11, bqA1, st1, 0, 0, 0);
                i32x4 api;
                api[0] = (int)cvtpk(__builtin_amdgcn_exp2f(st0[0]),
                                    __builtin_amdgcn_exp2f(st0[1]));
                api[1] = (int)cvtpk(__builtin_amdgcn_exp2f(st0[2]),
                                    __builtin_amdgcn_exp2f(st0[3]));
                api[2] = (int)cvtpk(__builtin_amdgcn_exp2f(st1[0]),
                                    __builtin_amdgcn_exp2f(st1[1]));
                api[3] = (int)cvtpk(__builtin_amdgcn_exp2f(st1[2]),
                                    __builtin_amdgcn_exp2f(st1[3]));
                s16x8 ap = __builtin_bit_cast(s16x8, api);
                laccA = __builtin_amdgcn_mfma_f32_16x16x32_bf16(ap, bones, laccA, 0, 0, 0);
#pragma unroll
                for (int c = 0; c < 4; ++c)
                    oA[c] = __builtin_amdgcn_mfma_f32_16x16x32_bf16(ap, bv[c], oA[c], 0, 0, 0);
            }
            {
                f32x4 st0 = {}, st1 = {};
                st0 = __builtin_amdgcn_mfma_f32_16x16x32_bf16(a00, bqB0, st0, 0, 0, 0);
                st0 = __builtin_amdgcn_mfma_f32_16x16x32_bf16(a01, bqB1, st0, 0, 0, 0);
                st1 = __builtin_amdgcn_mfma_f32_16x16x32_bf16(a10, bqB0, st1, 0, 0, 0);
                st1 = __builtin_amdgcn_mfma_f32_16x16x32_bf16(a11, bqB1, st1, 0, 0, 0);
                i32x4 api;
                api[0] = (int)cvtpk(__builtin_amdgcn_exp2f(st0[0]),
                                    __builtin_amdgcn_exp2f(st0[1]));
                api[1] = (int)cvtpk(__builtin_amdgcn_exp2f(st0[2]),
                                    __builtin_amdgcn_exp2f(st0[3]));
                api[2] = (int)cvtpk(__builtin_amdgcn_exp2f(st1[0]),
                                    __builtin_amdgcn_exp2f(st1[1]));
                api[3] = (int)cvtpk(__builtin_amdgcn_exp2f(st1[2]),
                                    __builtin_amdgcn_exp2f(st1[3]));
                s16x8 ap = __builtin_bit_cast(s16x8, api);
                laccB = __builtin_amdgcn_mfma_f32_16x16x32_bf16(ap, bones, laccB, 0, 0, 0);
#pragma unroll
                for (int c = 0; c < 4; ++c)
                    oB[c] = __builtin_amdgcn_mfma_f32_16x16x32_bf16(ap, bv[c], oB[c], 0, 0, 0);
            }
            __builtin_amdgcn_s_setprio(0);
        }
    };

    stage(Ksm[0], Vsm[0], 0);

#pragma unroll 1
    for (int jt = 0; jt < SEQL / 64; jt += 2) {
        const int j0 = jt * 64;
        stage(Ksm[1], Vsm[1], j0 + 64);
        WAITVM4();
        BAR();
        compute(Ksm[0], Vsm[0]);
        BAR();
        if (jt + 2 < SEQL / 64) {
            stage(Ksm[0], Vsm[0], j0 + 128);
            WAITVM4();
        } else {
            WAITVM0();
        }
        BAR();
        compute(Ksm[1], Vsm[1]);
        BAR();
    }

    float liA[4], liB[4];
#pragma unroll
    for (int r = 0; r < 4; ++r) {
        liA[r] = 1.0f / laccA[r];
        liB[r] = 1.0f / laccB[r];
    }

#pragma unroll
    for (int c = 0; c < 4; ++c) {
        const int d = c * 16 + l15;
#pragma unroll
        for (int r = 0; r < 4; ++r) {
            const int qr = quad * 4 + r;
            xqk[(size_t)(bb * SEQL + q0A + qr) * XSTR + h * HD + d] = f2bf(oA[c][r] * liA[r]);
            xqk[(size_t)(bb * SEQL + q0B + qr) * XSTR + h * HD + d] = f2bf(oB[c][r] * liB[r]);
        }
    }
}

// ---------------------------------------------------------------------------
// ws layout (u16 elems): xb [0,4M) | Wq|Wk|Wv|Wp [4M,8M) | bias fp32 @ 8M.
// ---------------------------------------------------------------------------
extern "C" void kernel_launch(void* const* d_in, const int* in_sizes, int n_in,
                              void* d_out, int out_size, void* d_ws, size_t ws_size,
                              hipStream_t stream) {
    const float* x  = (const float*)d_in[0];
    const float* Wq = (const float*)d_in[1];
    const float* bq = (const float*)d_in[2];
    const float* Wk = (const float*)d_in[3];
    const float* bk = (const float*)d_in[4];
    const float* Wv = (const float*)d_in[5];
    const float* bv = (const float*)d_in[6];
    const float* Wp = (const float*)d_in[7];
    const float* bp = (const float*)d_in[8];
    float* out = (float*)d_out;
    unsigned short* vtb = (unsigned short*)d_out;
    unsigned short* xqk = (unsigned short*)d_in[0];

    unsigned short* ws   = (unsigned short*)d_ws;
    const size_t XELT = (size_t)MTOT * DIMC;     // 4M
    const size_t WELT = (size_t)DIMC * DIMC;     // 1M
    unsigned short* xb   = ws;
    unsigned short* wall = ws + XELT;
    float*          ball = (float*)(ws + 2 * XELT);

    // allow 112 KB dynamic LDS for qkv8 (one-time)
    static bool ldsInit = false;
    if (!ldsInit) {
        (void)hipFuncSetAttribute((const void*)qkv8,
                                  hipFuncAttributeMaxDynamicSharedMemorySize,
                                  114688);
        ldsInit = true;
    }

    cast_all<<<8204, 256, 0, stream>>>(x, Wq, Wk, Wv, Wp, bq, bk, bv, xb, wall, ball);

    // fused QKV GEMM: M=4096, N=3072 -> 16 x 16 tiles of 256x192 = 256 blocks
    qkv8<<<256, 512, 114688, stream>>>(xb, wall, ball, xqk, vtb);

    // attention: 512 blocks (32 bh x 16 q-blocks of 128 rows), 4 waves each
    attn_fused<<<NB * NH * (SEQL / 128), 256, 0, stream>>>(xqk, vtb);

    // out-proj: M=4096, N=1024 -> 256 blocks, fp32 out
    gemm_tile<<<256, 256, 0, stream>>>(xqk, XSTR, wall + 3 * WELT, bp,
                                       nullptr, nullptr, out, 1);
}